// Round 1
// 2071.838 us; speedup vs baseline: 1.1928x; 1.1928x over previous
//
#include <hip/hip_runtime.h>

// Problem constants (reference file)
#define D   1024
#define H   16
#define DH  64
#define FF  4096
#define E   4
#define BSZ 2
#define TT  2048
#define NTOK (BSZ*TT)   // 4096 tokens

typedef unsigned short u16;
typedef __attribute__((ext_vector_type(8))) short bf16x8;   // 8 bf16 = 4 VGPRs (MFMA A/B frag)
typedef __attribute__((ext_vector_type(4))) float f32x4;    // MFMA C/D frag

__device__ __forceinline__ float us2f(u16 u) {
    return __uint_as_float(((unsigned int)u) << 16);  // bf16 -> f32 exact
}
__device__ __forceinline__ u16 f2bf_rn(float f) {     // f32 -> bf16 round-to-nearest-even
    unsigned u = __float_as_uint(f);
    return (u16)((u + 0x7FFFu + ((u >> 16) & 1u)) >> 16);
}

// async global->LDS, 16B per lane; LDS dest = wave-uniform base + lane*16
#define GLL16(gsrc, ldst) \
    __builtin_amdgcn_global_load_lds((const __attribute__((address_space(1))) void*)(gsrc), \
                                     (__attribute__((address_space(3))) void*)(ldst), 16, 0, 0)

// ---------------------------------------------------------------------------
// Dtype probe (R3-verified). Zero-inits expert counters.
// ---------------------------------------------------------------------------
__global__ __launch_bounds__(64) void probe_k(const unsigned* __restrict__ xw,
                                              int* __restrict__ meta) {
    const int lane = threadIdx.x;
    int wild = 0;
    for (int i = 0; i < 32; i++) {
        unsigned u = xw[lane * 32 + i];
        unsigned lo = u & 0xFFFFu;
        if ((lo & 0x7F80u) >= 0x5A00u) wild++;
    }
#pragma unroll
    for (int m = 32; m > 0; m >>= 1) wild += __shfl_xor(wild, m, 64);
    if (lane == 0) meta[4] = (wild < 64) ? 1 : 0;   // 1 = bf16 inputs, 0 = f32
    if (lane < 4) meta[lane] = 0;                   // expert counters
}

// ---------------------------------------------------------------------------
// Split a tensor into bf16 hi/lo pair (hi = rn(v), lo = rn(v - hi)).
// meta==nullptr -> input known f32; else dual-dtype via meta[4].
// ---------------------------------------------------------------------------
__global__ __launch_bounds__(256) void xsplit_k(const void* __restrict__ in,
    u16* __restrict__ hi, u16* __restrict__ lo, const int* __restrict__ meta)
{
    const int i = blockIdx.x * 256 + threadIdx.x;
    float4 v;
    if (meta && meta[4]) {
        ushort4 u = ((const ushort4*)in)[i];
        v = make_float4(us2f(u.x), us2f(u.y), us2f(u.z), us2f(u.w));
    } else {
        v = ((const float4*)in)[i];
    }
    ushort4 h, l;
    h.x = f2bf_rn(v.x); l.x = f2bf_rn(v.x - us2f(h.x));
    h.y = f2bf_rn(v.y); l.y = f2bf_rn(v.y - us2f(h.y));
    h.z = f2bf_rn(v.z); l.z = f2bf_rn(v.z - us2f(h.z));
    h.w = f2bf_rn(v.w); l.w = f2bf_rn(v.w - us2f(h.w));
    ((ushort4*)hi)[i] = h;
    ((ushort4*)lo)[i] = l;
}

// ---------------------------------------------------------------------------
// Weight transpose + bf16 split: W[e][K][N] (dual dtype) -> T{hi,lo}[e][N][K].
// 64x64 tiles through padded LDS. Grid: (K/64, N/64, E).
// ---------------------------------------------------------------------------
__global__ __launch_bounds__(256) void wtrans_k(const void* __restrict__ Wsrc,
    u16* __restrict__ Thi, u16* __restrict__ Tlo,
    int K, int N, const int* __restrict__ meta)
{
    const int bfm = meta[4];
    const int e = blockIdx.z;
    const int k0 = blockIdx.x * 64, n0 = blockIdx.y * 64;
    __shared__ float t[64][65];
    const int tid = threadIdx.x;
    const size_t sbase = (size_t)e * K * N;
#pragma unroll
    for (int rr = 0; rr < 4; rr++) {
        int row = rr * 16 + (tid >> 4);      // k
        int c4  = (tid & 15) * 4;            // n
        size_t off = sbase + (size_t)(k0 + row) * N + n0 + c4;
        float4 v;
        if (bfm) {
            ushort4 u = *(const ushort4*)((const u16*)Wsrc + off);
            v = make_float4(us2f(u.x), us2f(u.y), us2f(u.z), us2f(u.w));
        } else {
            v = *(const float4*)((const float*)Wsrc + off);
        }
        t[row][c4 + 0] = v.x; t[row][c4 + 1] = v.y;
        t[row][c4 + 2] = v.z; t[row][c4 + 3] = v.w;
    }
    __syncthreads();
    const size_t dbase = (size_t)e * K * N;  // transposed [N][K]
#pragma unroll
    for (int rr = 0; rr < 4; rr++) {
        int nrow = rr * 16 + (tid >> 4);
        int k4   = (tid & 15) * 4;
        ushort4 h, l;
        float f0 = t[k4 + 0][nrow], f1 = t[k4 + 1][nrow];
        float f2 = t[k4 + 2][nrow], f3 = t[k4 + 3][nrow];
        h.x = f2bf_rn(f0); l.x = f2bf_rn(f0 - us2f(h.x));
        h.y = f2bf_rn(f1); l.y = f2bf_rn(f1 - us2f(h.y));
        h.z = f2bf_rn(f2); l.z = f2bf_rn(f2 - us2f(h.z));
        h.w = f2bf_rn(f3); l.w = f2bf_rn(f3 - us2f(h.w));
        size_t doff = dbase + (size_t)(n0 + nrow) * K + k0 + k4;
        *(ushort4*)&Thi[doff] = h;
        *(ushort4*)&Tlo[doff] = l;
    }
}

// ---------------------------------------------------------------------------
// MFMA GEMM, split-bf16 precision: C = (Ahi+Alo)(Bhi+Blo) ~ 3-term compensation.
//   C[M,N] = A[M,K] * B^T[N,K] + bias; fp32 accumulate in AGPRs.
//   128x128 tile, BK=32, 256 threads = 4 waves (2x2 of 64x64 each),
//   16x16x32 bf16 MFMA, 4x4 fragments per wave, 48 MFMA / K-step / wave.
//   Staging: global_load_lds w16 into [kchunk][row][8] LDS (16-lane groups
//   read 256B-contiguous ds_read_b128 -> conflict-free).
//   MoE support via rowlist/rowcnt (token indirection), dual-dtype bias,
//   optional f32 residual, relu, and bf16 hi/lo split output (for h).
// ---------------------------------------------------------------------------
__global__ __launch_bounds__(256) void mgemm_k(
    const u16* __restrict__ Ahi, const u16* __restrict__ Alo,
    const u16* __restrict__ Bhi, const u16* __restrict__ Blo,   // [e][N][K]
    const void* __restrict__ bias,                              // dual dtype [e][N]
    float* __restrict__ Cf,                                     // f32 out (or null)
    u16* __restrict__ Chi, u16* __restrict__ Clo,               // bf16 split out
    const float* __restrict__ resid,
    const int* __restrict__ rowlist, const int* __restrict__ rowcnt,
    const int* __restrict__ meta, int M, int N, int K, int relu)
{
    const int bfm = meta[4];
    const int e = blockIdx.z;
    const int cnt = rowcnt ? rowcnt[e] : M;
    const int m0 = blockIdx.y * 128;
    if (m0 >= cnt) return;
    const int n0 = blockIdx.x * 128;
    const int* lp = rowlist ? (rowlist + e * NTOK) : nullptr;

    __shared__ __attribute__((aligned(16))) u16 AhiL[4][128][8];
    __shared__ __attribute__((aligned(16))) u16 AloL[4][128][8];
    __shared__ __attribute__((aligned(16))) u16 BhL[4][128][8];
    __shared__ __attribute__((aligned(16))) u16 BlL[4][128][8];

    const int tid = threadIdx.x;
    const int wave = tid >> 6, lane = tid & 63;
    const int wm = wave >> 1, wn = wave & 1;

    // Per-wave staging assignment: w0=Ahi, w1=Alo, w2=Bhi, w3=Blo (8 GLL16 each)
    const char* sptr;
    size_t soff0, soff1;
    u16* dbase;
    if (wave < 2) {
        int r0 = m0 + lane;      if (r0 >= cnt) r0 = cnt - 1;
        int r1 = m0 + 64 + lane; if (r1 >= cnt) r1 = cnt - 1;
        int t0 = lp ? lp[r0] : r0;
        int t1 = lp ? lp[r1] : r1;
        sptr  = (const char*)(wave ? Alo : Ahi);
        soff0 = (size_t)t0 * K * 2;
        soff1 = (size_t)t1 * K * 2;
        dbase = wave ? &AloL[0][0][0] : &AhiL[0][0][0];
    } else {
        sptr  = (const char*)(((wave == 3) ? Blo : Bhi) + (size_t)e * N * K);
        soff0 = (size_t)(n0 + lane) * K * 2;
        soff1 = (size_t)(n0 + 64 + lane) * K * 2;
        dbase = (wave == 3) ? &BlL[0][0][0] : &BhL[0][0][0];
    }

    f32x4 acc[4][4];
#pragma unroll
    for (int mi = 0; mi < 4; mi++)
#pragma unroll
        for (int ni = 0; ni < 4; ni++) acc[mi][ni] = (f32x4){0.f, 0.f, 0.f, 0.f};

    const int lrow = lane & 15, kcl = lane >> 4;

    for (int k0 = 0; k0 < K; k0 += 32) {
        __syncthreads();                     // prev iter's ds_reads done; LDS reusable
        const size_t kb = (size_t)k0 * 2;
#pragma unroll
        for (int kc = 0; kc < 4; kc++) {     // each wave stages its array, both halves
            GLL16(sptr + soff0 + kb + kc * 16, dbase + kc * 1024);
            GLL16(sptr + soff1 + kb + kc * 16, dbase + kc * 1024 + 512);
        }
        __syncthreads();                     // compiler drains vmcnt before barrier

        bf16x8 ah[4], al[4];
#pragma unroll
        for (int mi = 0; mi < 4; mi++) {
            int r = wm * 64 + mi * 16 + lrow;
            ah[mi] = *(const bf16x8*)&AhiL[kcl][r][0];
            al[mi] = *(const bf16x8*)&AloL[kcl][r][0];
        }
#pragma unroll
        for (int ni = 0; ni < 4; ni++) {
            int c = wn * 64 + ni * 16 + lrow;
            bf16x8 bh = *(const bf16x8*)&BhL[kcl][c][0];
            bf16x8 bl = *(const bf16x8*)&BlL[kcl][c][0];
#pragma unroll
            for (int mi = 0; mi < 4; mi++) {
                acc[mi][ni] = __builtin_amdgcn_mfma_f32_16x16x32_bf16(ah[mi], bh, acc[mi][ni], 0, 0, 0);
                acc[mi][ni] = __builtin_amdgcn_mfma_f32_16x16x32_bf16(al[mi], bh, acc[mi][ni], 0, 0, 0);
                acc[mi][ni] = __builtin_amdgcn_mfma_f32_16x16x32_bf16(ah[mi], bl, acc[mi][ni], 0, 0, 0);
            }
        }
    }

    // Epilogue. C/D frag layout (verified): col = lane&15, row = (lane>>4)*4 + reg.
    float bval[4];
#pragma unroll
    for (int ni = 0; ni < 4; ni++) {
        int col = n0 + wn * 64 + ni * 16 + (lane & 15);
        bval[ni] = bfm ? us2f(((const u16*)bias)[(size_t)e * N + col])
                       : ((const float*)bias)[(size_t)e * N + col];
    }
#pragma unroll
    for (int mi = 0; mi < 4; mi++) {
#pragma unroll
        for (int rg = 0; rg < 4; rg++) {
            int row = m0 + wm * 64 + mi * 16 + (lane >> 4) * 4 + rg;
            if (row >= cnt) continue;
            int tok = lp ? lp[row] : row;
#pragma unroll
            for (int ni = 0; ni < 4; ni++) {
                int col = n0 + wn * 64 + ni * 16 + (lane & 15);
                float v = acc[mi][ni][rg] + bval[ni];
                size_t off = (size_t)tok * N + col;
                if (resid) v += resid[off];
                if (relu) v = fmaxf(v, 0.f);
                if (Cf) {
                    Cf[off] = v;
                } else {
                    u16 hh = f2bf_rn(v);
                    Chi[off] = hh;
                    Clo[off] = f2bf_rn(v - us2f(hh));
                }
            }
        }
    }
}

// ---------------------------------------------------------------------------
// Tiled causal flash attention (fp32 VALU, unchanged math). Epilogue now
// emits bf16 hi/lo split directly (feeds the Wo MFMA GEMM).
// ---------------------------------------------------------------------------
__global__ __launch_bounds__(256) void attn_tile(const float* __restrict__ q,
    const float* __restrict__ k, const float* __restrict__ v,
    u16* __restrict__ ohi, u16* __restrict__ olo)
{
    const int qi = (int)gridDim.x - 1 - (int)blockIdx.x;  // heavy tiles first
    const int bh = blockIdx.y;
    const int b = bh >> 4, h = bh & 15;
    const size_t base = (size_t)b * TT * D + (size_t)h * DH;

    __shared__ float Qs[64][64];    // [d][q]
    __shared__ float KPs[64][64];   // K as [d][k], then P as [kk][q]
    __shared__ float Vs[64][64];    // [kk][d]
    __shared__ float red[64][17];
    __shared__ float mrow[64], lrow[64], arow[64];

    const int tid = threadIdx.x;
    const int tx = tid & 15, ty = tid >> 4;
    const int tx4 = tx << 2, ty4 = ty << 2;
    const int sr = tid >> 2;
    const int sc = (tid & 3) << 4;

    {
        const float* qrow = q + base + (size_t)(qi * 64 + sr) * D;
#pragma unroll
        for (int r = 0; r < 4; r++) {
            int d0 = sc + (r << 2);
            float4 qv = *(const float4*)(qrow + d0);
            Qs[d0 + 0][sr] = qv.x * 0.125f; Qs[d0 + 1][sr] = qv.y * 0.125f;
            Qs[d0 + 2][sr] = qv.z * 0.125f; Qs[d0 + 3][sr] = qv.w * 0.125f;
        }
    }
    if (tid < 64) { mrow[tid] = -1e30f; lrow[tid] = 0.f; }

    float o[4][4];
#pragma unroll
    for (int i = 0; i < 4; i++)
#pragma unroll
        for (int j = 0; j < 4; j++) o[i][j] = 0.f;

    for (int kt = 0; kt <= qi; ++kt) {
        __syncthreads();
        {
            const float* krow = k + base + (size_t)(kt * 64 + sr) * D;
            const float* vrow = v + base + (size_t)(kt * 64 + sr) * D;
#pragma unroll
            for (int r = 0; r < 4; r++) {
                int d0 = sc + (r << 2);
                float4 kv = *(const float4*)(krow + d0);
                KPs[d0 + 0][sr] = kv.x; KPs[d0 + 1][sr] = kv.y;
                KPs[d0 + 2][sr] = kv.z; KPs[d0 + 3][sr] = kv.w;
                *(float4*)&Vs[sr][d0] = *(const float4*)(vrow + d0);
            }
        }
        __syncthreads();

        float s[4][4];
#pragma unroll
        for (int i = 0; i < 4; i++)
#pragma unroll
            for (int j = 0; j < 4; j++) s[i][j] = 0.f;
        for (int d = 0; d < 64; d++) {
            float4 a4 = *(const float4*)&Qs[d][ty4];
            float4 b4 = *(const float4*)&KPs[d][tx4];
            s[0][0] += a4.x * b4.x; s[0][1] += a4.x * b4.y; s[0][2] += a4.x * b4.z; s[0][3] += a4.x * b4.w;
            s[1][0] += a4.y * b4.x; s[1][1] += a4.y * b4.y; s[1][2] += a4.y * b4.z; s[1][3] += a4.y * b4.w;
            s[2][0] += a4.z * b4.x; s[2][1] += a4.z * b4.y; s[2][2] += a4.z * b4.z; s[2][3] += a4.z * b4.w;
            s[3][0] += a4.w * b4.x; s[3][1] += a4.w * b4.y; s[3][2] += a4.w * b4.z; s[3][3] += a4.w * b4.w;
        }
        if (kt == qi) {
#pragma unroll
            for (int i = 0; i < 4; i++)
#pragma unroll
                for (int j = 0; j < 4; j++)
                    if (ty4 + i < tx4 + j) s[i][j] = -1e30f;
        }
#pragma unroll
        for (int i = 0; i < 4; i++)
            red[ty4 + i][tx] = fmaxf(fmaxf(s[i][0], s[i][1]), fmaxf(s[i][2], s[i][3]));
        __syncthreads();
        if (tid < 64) {
            float rm = red[tid][0];
#pragma unroll
            for (int t = 1; t < 16; t++) rm = fmaxf(rm, red[tid][t]);
            float mo = mrow[tid];
            float mn = fmaxf(mo, rm);
            arow[tid] = (mo < -9e29f) ? 0.f : __expf(mo - mn);
            mrow[tid] = mn;
        }
        __syncthreads();
#pragma unroll
        for (int i = 0; i < 4; i++) {
            float mi = mrow[ty4 + i];
            float rs = 0.f;
#pragma unroll
            for (int j = 0; j < 4; j++) {
                float p = __expf(fmaxf(s[i][j] - mi, -80.f));
                KPs[tx4 + j][ty4 + i] = p;
                rs += p;
            }
            red[ty4 + i][tx] = rs;
        }
        __syncthreads();
        if (tid < 64) {
            float rs = 0.f;
#pragma unroll
            for (int t = 0; t < 16; t++) rs += red[tid][t];
            lrow[tid] = lrow[tid] * arow[tid] + rs;
        }
        {
            float a0 = arow[ty4 + 0], a1 = arow[ty4 + 1], a2 = arow[ty4 + 2], a3 = arow[ty4 + 3];
#pragma unroll
            for (int j = 0; j < 4; j++) { o[0][j] *= a0; o[1][j] *= a1; o[2][j] *= a2; o[3][j] *= a3; }
        }
        for (int kk = 0; kk < 64; kk++) {
            float4 a4 = *(const float4*)&KPs[kk][ty4];
            float4 b4 = *(const float4*)&Vs[kk][tx4];
            o[0][0] += a4.x * b4.x; o[0][1] += a4.x * b4.y; o[0][2] += a4.x * b4.z; o[0][3] += a4.x * b4.w;
            o[1][0] += a4.y * b4.x; o[1][1] += a4.y * b4.y; o[1][2] += a4.y * b4.z; o[1][3] += a4.y * b4.w;
            o[2][0] += a4.z * b4.x; o[2][1] += a4.z * b4.y; o[2][2] += a4.z * b4.z; o[2][3] += a4.z * b4.w;
            o[3][0] += a4.w * b4.x; o[3][1] += a4.w * b4.y; o[3][2] += a4.w * b4.z; o[3][3] += a4.w * b4.w;
        }
    }
    __syncthreads();
#pragma unroll
    for (int i = 0; i < 4; i++) {
        float inv = 1.f / lrow[ty4 + i];
        ushort4 h4, l4;
        float vv;
        vv = o[i][0] * inv; h4.x = f2bf_rn(vv); l4.x = f2bf_rn(vv - us2f(h4.x));
        vv = o[i][1] * inv; h4.y = f2bf_rn(vv); l4.y = f2bf_rn(vv - us2f(h4.y));
        vv = o[i][2] * inv; h4.z = f2bf_rn(vv); l4.z = f2bf_rn(vv - us2f(h4.z));
        vv = o[i][3] * inv; h4.w = f2bf_rn(vv); l4.w = f2bf_rn(vv - us2f(h4.w));
        size_t oidx = base + (size_t)(qi * 64 + ty4 + i) * D + tx4;
        *(ushort4*)&ohi[oidx] = h4;
        *(ushort4*)&olo[oidx] = l4;
    }
}

// ---------------------------------------------------------------------------
// LayerNorm over D=1024 (in-place safe). Residual optionally dual-dtype raw input.
// ---------------------------------------------------------------------------
__global__ __launch_bounds__(256) void layernorm_k(const float* __restrict__ a,
    const void* __restrict__ resid, int rdual, const void* __restrict__ g_,
    const void* __restrict__ b_, float* __restrict__ out,
    const int* __restrict__ meta)
{
    const int bfm = meta[4];
    const int row = blockIdx.x;
    const int tid = threadIdx.x;
    float vals[4];
    float s = 0.f, s2 = 0.f;
#pragma unroll
    for (int i = 0; i < 4; i++) {
        int idx = tid + (i << 8);
        size_t off = (size_t)row * D + idx;
        float v = a[off];
        if (resid) {
            float rv = (rdual && bfm) ? us2f(((const u16*)resid)[off])
                                      : ((const float*)resid)[off];
            v += rv;
        }
        vals[i] = v; s += v; s2 += v * v;
    }
#pragma unroll
    for (int msk = 32; msk > 0; msk >>= 1) {
        s  += __shfl_xor(s,  msk, 64);
        s2 += __shfl_xor(s2, msk, 64);
    }
    __shared__ float red[2][4];
    if ((tid & 63) == 0) { red[0][tid >> 6] = s; red[1][tid >> 6] = s2; }
    __syncthreads();
    s  = red[0][0] + red[0][1] + red[0][2] + red[0][3];
    s2 = red[1][0] + red[1][1] + red[1][2] + red[1][3];
    const float mu = s * (1.f / D);
    const float var = s2 * (1.f / D) - mu * mu;
    const float rs = rsqrtf(var + 1e-5f);
#pragma unroll
    for (int i = 0; i < 4; i++) {
        int idx = tid + (i << 8);
        float gg = bfm ? us2f(((const u16*)g_)[idx]) : ((const float*)g_)[idx];
        float bb = bfm ? us2f(((const u16*)b_)[idx]) : ((const float*)b_)[idx];
        out[(size_t)row * D + idx] = (vals[i] - mu) * rs * gg + bb;
    }
}

// ---------------------------------------------------------------------------
// Top-1 gate in fp32 + bucket scatter. One wave per token.
// ---------------------------------------------------------------------------
__global__ __launch_bounds__(256) void gate_k(const float* __restrict__ x1,
    const void* __restrict__ Wg, const void* __restrict__ bg,
    int* __restrict__ cnt, int* __restrict__ list, const int* __restrict__ meta)
{
    const int bfm = meta[4];
    const int tok = (blockIdx.x * 256 + threadIdx.x) >> 6;
    const int lane = threadIdx.x & 63;
    const float* xr = x1 + (size_t)tok * D;
    float s0 = 0.f, s1 = 0.f, s2 = 0.f, s3 = 0.f;
    for (int d = lane; d < D; d += 64) {
        float xv = xr[d];
        float w0, w1, w2, w3;
        if (bfm) {
            ushort4 wu = ((const ushort4*)Wg)[d];
            w0 = us2f(wu.x); w1 = us2f(wu.y); w2 = us2f(wu.z); w3 = us2f(wu.w);
        } else {
            float4 wf = ((const float4*)Wg)[d];
            w0 = wf.x; w1 = wf.y; w2 = wf.z; w3 = wf.w;
        }
        s0 += xv * w0; s1 += xv * w1; s2 += xv * w2; s3 += xv * w3;
    }
#pragma unroll
    for (int msk = 32; msk > 0; msk >>= 1) {
        s0 += __shfl_xor(s0, msk, 64); s1 += __shfl_xor(s1, msk, 64);
        s2 += __shfl_xor(s2, msk, 64); s3 += __shfl_xor(s3, msk, 64);
    }
    if (lane == 0) {
        float g0, g1, g2, g3;
        if (bfm) {
            g0 = us2f(((const u16*)bg)[0]); g1 = us2f(((const u16*)bg)[1]);
            g2 = us2f(((const u16*)bg)[2]); g3 = us2f(((const u16*)bg)[3]);
        } else {
            g0 = ((const float*)bg)[0]; g1 = ((const float*)bg)[1];
            g2 = ((const float*)bg)[2]; g3 = ((const float*)bg)[3];
        }
        float b0 = s0 + g0, b1 = s1 + g1, b2 = s2 + g2, b3 = s3 + g3;
        int bi = 0; float best = b0;
        if (b1 > best) { best = b1; bi = 1; }
        if (b2 > best) { best = b2; bi = 2; }
        if (b3 > best) { best = b3; bi = 3; }
        int slot = atomicAdd(&cnt[bi], 1);
        list[bi * NTOK + slot] = tok;
    }
}

// ---------------------------------------------------------------------------
extern "C" void kernel_launch(void* const* d_in, const int* in_sizes, int n_in,
                              void* d_out, int out_size, void* d_ws, size_t ws_size,
                              hipStream_t stream)
{
    const void* x  = d_in[0];
    const void* Wq = d_in[2];  const void* bq = d_in[3];
    const void* Wk = d_in[4];  const void* bk = d_in[5];
    const void* Wv = d_in[6];  const void* bv = d_in[7];
    const void* Wo = d_in[8];  const void* bo = d_in[9];
    const void* g1 = d_in[10]; const void* b1 = d_in[11];
    const void* Wg = d_in[12]; const void* bg = d_in[13];
    const void* W1e = d_in[14]; const void* b1e = d_in[15];
    const void* W2e = d_in[16]; const void* b2e = d_in[17];
    const void* g2 = d_in[18]; const void* b2 = d_in[19];

    const size_t NE  = (size_t)NTOK * D;   // 4M elems
    const size_t NE4 = NE * 4;             // bytes per f32 buffer
    char* W = (char*)d_ws;
    // [0, NE4)            : xf  = x1 (f32)
    // [NE4, 5*NE4)        : buf0..buf3 (f32; also h hi/lo span, attn-out hi/lo)
    // [5*NE4, +128K)      : meta + expert lists
    // next 16.8MB         : xhi/xlo (bf16 split of current A activations)
    // next 67MB           : weight scratch: whi | wlo (transposed bf16 split)
    float* xf   = (float*)W;
    float* buf0 = (float*)(W + 1 * NE4);
    float* buf1 = (float*)(W + 2 * NE4);
    float* buf2 = (float*)(W + 3 * NE4);
    float* buf3 = (float*)(W + 4 * NE4);
    int* meta = (int*)(W + 5 * NE4);
    int* list = meta + 16;
    u16* xhi = (u16*)(W + 5 * NE4 + (size_t)131072);
    u16* xlo = xhi + NE;
    u16* whi = xlo + NE;
    u16* wlo = whi + (size_t)NTOK * FF;    // 16.8M elems each
    u16* ahi = (u16*)buf3;  u16* aloA = ahi + NE;           // attn out split
    u16* hhi = (u16*)buf0;  u16* hlo = hhi + (size_t)NTOK * FF;  // h split
    float* outf = (float*)d_out;

    probe_k<<<1, 64, 0, stream>>>((const unsigned*)x, meta);
    xsplit_k<<<(int)(NE / 4 / 256), 256, 0, stream>>>(x, xhi, xlo, meta);

    const size_t DD = (size_t)D * D;
    wtrans_k<<<dim3(D / 64, D / 64, 1), 256, 0, stream>>>(Wq, whi + 0 * DD, wlo + 0 * DD, D, D, meta);
    wtrans_k<<<dim3(D / 64, D / 64, 1), 256, 0, stream>>>(Wk, whi + 1 * DD, wlo + 1 * DD, D, D, meta);
    wtrans_k<<<dim3(D / 64, D / 64, 1), 256, 0, stream>>>(Wv, whi + 2 * DD, wlo + 2 * DD, D, D, meta);
    wtrans_k<<<dim3(D / 64, D / 64, 1), 256, 0, stream>>>(Wo, whi + 3 * DD, wlo + 3 * DD, D, D, meta);

    dim3 gqkv(D / 128, NTOK / 128, 1);
    mgemm_k<<<gqkv, 256, 0, stream>>>(xhi, xlo, whi + 0 * DD, wlo + 0 * DD, bq, buf0,
                                      nullptr, nullptr, nullptr, nullptr, nullptr, meta, NTOK, D, D, 0);
    mgemm_k<<<gqkv, 256, 0, stream>>>(xhi, xlo, whi + 1 * DD, wlo + 1 * DD, bk, buf1,
                                      nullptr, nullptr, nullptr, nullptr, nullptr, meta, NTOK, D, D, 0);
    mgemm_k<<<gqkv, 256, 0, stream>>>(xhi, xlo, whi + 2 * DD, wlo + 2 * DD, bv, buf2,
                                      nullptr, nullptr, nullptr, nullptr, nullptr, meta, NTOK, D, D, 0);

    attn_tile<<<dim3(TT / 64, BSZ * H), 256, 0, stream>>>(buf0, buf1, buf2, ahi, aloA);

    mgemm_k<<<gqkv, 256, 0, stream>>>(ahi, aloA, whi + 3 * DD, wlo + 3 * DD, bo, buf0,
                                      nullptr, nullptr, nullptr, nullptr, nullptr, meta, NTOK, D, D, 0);
    layernorm_k<<<NTOK, 256, 0, stream>>>(buf0, x, 1, g1, b1, xf, meta);

    gate_k<<<NTOK / 4, 256, 0, stream>>>(xf, Wg, bg, meta, list, meta);
    xsplit_k<<<(int)(NE / 4 / 256), 256, 0, stream>>>(xf, xhi, xlo, nullptr);

    wtrans_k<<<dim3(D / 64, FF / 64, E), 256, 0, stream>>>(W1e, whi, wlo, D, FF, meta);
    mgemm_k<<<dim3(FF / 128, NTOK / 128, E), 256, 0, stream>>>(xhi, xlo, whi, wlo, b1e,
                                      nullptr, hhi, hlo, nullptr, list, meta, meta, NTOK, FF, D, 1);

    wtrans_k<<<dim3(FF / 64, D / 64, E), 256, 0, stream>>>(W2e, whi, wlo, FF, D, meta);
    mgemm_k<<<dim3(D / 128, NTOK / 128, E), 256, 0, stream>>>(hhi, hlo, whi, wlo, b2e,
                                      outf, nullptr, nullptr, xf, list, meta, meta, NTOK, D, FF, 0);

    layernorm_k<<<NTOK, 256, 0, stream>>>(outf, nullptr, 0, g2, b2, outf, meta);
}

// Round 4
// 1665.485 us; speedup vs baseline: 1.4838x; 1.2440x over previous
//
#include <hip/hip_runtime.h>

// Problem constants (reference file)
#define D   1024
#define H   16
#define DH  64
#define FF  4096
#define E   4
#define BSZ 2
#define TT  2048
#define NTOK (BSZ*TT)   // 4096 tokens

typedef unsigned short u16;
typedef __attribute__((ext_vector_type(8))) short bf16x8;   // 8 bf16 = 4 VGPRs (MFMA A/B frag)
typedef __attribute__((ext_vector_type(4))) float f32x4;    // MFMA C/D frag

__device__ __forceinline__ float us2f(u16 u) {
    return __uint_as_float(((unsigned int)u) << 16);  // bf16 -> f32 exact
}
__device__ __forceinline__ u16 f2bf_rn(float f) {     // f32 -> bf16 round-to-nearest-even
    unsigned u = __float_as_uint(f);
    return (u16)((u + 0x7FFFu + ((u >> 16) & 1u)) >> 16);
}

// async global->LDS, 16B per lane; LDS dest = wave-uniform base + lane*16
#define GLL16(gsrc, ldst) \
    __builtin_amdgcn_global_load_lds((const __attribute__((address_space(1))) void*)(gsrc), \
                                     (__attribute__((address_space(3))) void*)(ldst), 16, 0, 0)

// ---------------------------------------------------------------------------
// Dtype probe. Zero-inits expert counters.
// ---------------------------------------------------------------------------
__global__ __launch_bounds__(64) void probe_k(const unsigned* __restrict__ xw,
                                              int* __restrict__ meta) {
    const int lane = threadIdx.x;
    int wild = 0;
    for (int i = 0; i < 32; i++) {
        unsigned u = xw[lane * 32 + i];
        unsigned lo = u & 0xFFFFu;
        if ((lo & 0x7F80u) >= 0x5A00u) wild++;
    }
#pragma unroll
    for (int m = 32; m > 0; m >>= 1) wild += __shfl_xor(wild, m, 64);
    if (lane == 0) meta[4] = (wild < 64) ? 1 : 0;   // 1 = bf16 inputs, 0 = f32
    if (lane < 4) meta[lane] = 0;                   // expert counters
}

// ---------------------------------------------------------------------------
// Split a tensor into bf16 hi/lo pair (hi = rn(v), lo = rn(v - hi)).
// ---------------------------------------------------------------------------
__global__ __launch_bounds__(256) void xsplit_k(const void* __restrict__ in,
    u16* __restrict__ hi, u16* __restrict__ lo, const int* __restrict__ meta)
{
    const int i = blockIdx.x * 256 + threadIdx.x;
    float4 v;
    if (meta && meta[4]) {
        ushort4 u = ((const ushort4*)in)[i];
        v = make_float4(us2f(u.x), us2f(u.y), us2f(u.z), us2f(u.w));
    } else {
        v = ((const float4*)in)[i];
    }
    ushort4 h, l;
    h.x = f2bf_rn(v.x); l.x = f2bf_rn(v.x - us2f(h.x));
    h.y = f2bf_rn(v.y); l.y = f2bf_rn(v.y - us2f(h.y));
    h.z = f2bf_rn(v.z); l.z = f2bf_rn(v.z - us2f(h.z));
    h.w = f2bf_rn(v.w); l.w = f2bf_rn(v.w - us2f(h.w));
    ((ushort4*)hi)[i] = h;
    ((ushort4*)lo)[i] = l;
}

// ---------------------------------------------------------------------------
// Weight transpose + bf16 split: W[e][K][N] (dual dtype) -> T{hi,lo}[e][N][K].
// ---------------------------------------------------------------------------
__global__ __launch_bounds__(256) void wtrans_k(const void* __restrict__ Wsrc,
    u16* __restrict__ Thi, u16* __restrict__ Tlo,
    int K, int N, const int* __restrict__ meta)
{
    const int bfm = meta[4];
    const int e = blockIdx.z;
    const int k0 = blockIdx.x * 64, n0 = blockIdx.y * 64;
    __shared__ float t[64][65];
    const int tid = threadIdx.x;
    const size_t sbase = (size_t)e * K * N;
#pragma unroll
    for (int rr = 0; rr < 4; rr++) {
        int row = rr * 16 + (tid >> 4);      // k
        int c4  = (tid & 15) * 4;            // n
        size_t off = sbase + (size_t)(k0 + row) * N + n0 + c4;
        float4 v;
        if (bfm) {
            ushort4 u = *(const ushort4*)((const u16*)Wsrc + off);
            v = make_float4(us2f(u.x), us2f(u.y), us2f(u.z), us2f(u.w));
        } else {
            v = *(const float4*)((const float*)Wsrc + off);
        }
        t[row][c4 + 0] = v.x; t[row][c4 + 1] = v.y;
        t[row][c4 + 2] = v.z; t[row][c4 + 3] = v.w;
    }
    __syncthreads();
    const size_t dbase = (size_t)e * K * N;  // transposed [N][K]
#pragma unroll
    for (int rr = 0; rr < 4; rr++) {
        int nrow = rr * 16 + (tid >> 4);
        int k4   = (tid & 15) * 4;
        ushort4 h, l;
        float f0 = t[k4 + 0][nrow], f1 = t[k4 + 1][nrow];
        float f2 = t[k4 + 2][nrow], f3 = t[k4 + 3][nrow];
        h.x = f2bf_rn(f0); l.x = f2bf_rn(f0 - us2f(h.x));
        h.y = f2bf_rn(f1); l.y = f2bf_rn(f1 - us2f(h.y));
        h.z = f2bf_rn(f2); l.z = f2bf_rn(f2 - us2f(h.z));
        h.w = f2bf_rn(f3); l.w = f2bf_rn(f3 - us2f(h.w));
        size_t doff = dbase + (size_t)(n0 + nrow) * K + k0 + k4;
        *(ushort4*)&Thi[doff] = h;
        *(ushort4*)&Tlo[doff] = l;
    }
}

// ---------------------------------------------------------------------------
// MFMA GEMM, split-bf16 (Ahi+Alo)(Bhi+Blo) 3-term compensation.
//   C[M,N] = A[M,K] * B^T[N,K] + bias; 128x128 tile, BK=32, 4 waves.
//   bias_row: bias indexed by output ROW (for transposed-output GEMMs).
// ---------------------------------------------------------------------------
template<int TERMS>
__global__ __launch_bounds__(256) void mgemm_k(
    const u16* __restrict__ Ahi, const u16* __restrict__ Alo,
    const u16* __restrict__ Bhi, const u16* __restrict__ Blo,   // [e][N][K]
    const void* __restrict__ bias,                              // dual dtype
    float* __restrict__ Cf,                                     // f32 out (or null)
    u16* __restrict__ Chi, u16* __restrict__ Clo,               // bf16 out (Clo opt)
    const float* __restrict__ resid,
    const int* __restrict__ rowlist, const int* __restrict__ rowcnt,
    const int* __restrict__ meta, int M, int N, int K, int relu, int bias_row)
{
    const int bfm = meta[4];
    const int e = blockIdx.z;
    const int cnt = rowcnt ? rowcnt[e] : M;
    const int m0 = blockIdx.y * 128;
    if (m0 >= cnt) return;
    const int n0 = blockIdx.x * 128;
    const int* lp = rowlist ? (rowlist + e * NTOK) : nullptr;

    __shared__ __attribute__((aligned(16))) u16 AhiL[4][128][8];
    __shared__ __attribute__((aligned(16))) u16 AloL[4][128][8];
    __shared__ __attribute__((aligned(16))) u16 BhL[4][128][8];
    __shared__ __attribute__((aligned(16))) u16 BlL[4][128][8];

    const int tid = threadIdx.x;
    const int wave = tid >> 6, lane = tid & 63;
    const int wm = wave >> 1, wn = wave & 1;

    // Per-wave staging: w0=Ahi, w1=Alo, w2=Bhi, w3=Blo (8 GLL16 each)
    const char* sptr;
    size_t soff0 = 0, soff1 = 0;
    u16* dbase;
    if (wave < 2) {
        int r0 = m0 + lane;      if (r0 >= cnt) r0 = cnt - 1;
        int r1 = m0 + 64 + lane; if (r1 >= cnt) r1 = cnt - 1;
        int t0 = lp ? lp[r0] : r0;
        int t1 = lp ? lp[r1] : r1;
        sptr  = (const char*)(wave ? Alo : Ahi);
        soff0 = (size_t)t0 * K * 2;
        soff1 = (size_t)t1 * K * 2;
        dbase = wave ? &AloL[0][0][0] : &AhiL[0][0][0];
    } else {
        sptr  = (const char*)(((wave == 3) ? Blo : Bhi) + (size_t)e * N * K);
        soff0 = (size_t)(n0 + lane) * K * 2;
        soff1 = (size_t)(n0 + 64 + lane) * K * 2;
        dbase = (wave == 3) ? &BlL[0][0][0] : &BhL[0][0][0];
    }

    f32x4 acc[4][4];
#pragma unroll
    for (int mi = 0; mi < 4; mi++)
#pragma unroll
        for (int ni = 0; ni < 4; ni++) acc[mi][ni] = (f32x4){0.f, 0.f, 0.f, 0.f};

    const int lrow = lane & 15, kcl = lane >> 4;

    for (int k0 = 0; k0 < K; k0 += 32) {
        __syncthreads();
        const size_t kb = (size_t)k0 * 2;
#pragma unroll
        for (int kc = 0; kc < 4; kc++) {
            GLL16(sptr + soff0 + kb + kc * 16, dbase + kc * 1024);
            GLL16(sptr + soff1 + kb + kc * 16, dbase + kc * 1024 + 512);
        }
        __syncthreads();

        bf16x8 ah[4], al[4];
#pragma unroll
        for (int mi = 0; mi < 4; mi++) {
            int r = wm * 64 + mi * 16 + lrow;
            ah[mi] = *(const bf16x8*)&AhiL[kcl][r][0];
            al[mi] = *(const bf16x8*)&AloL[kcl][r][0];
        }
#pragma unroll
        for (int ni = 0; ni < 4; ni++) {
            int c = wn * 64 + ni * 16 + lrow;
            bf16x8 bh = *(const bf16x8*)&BhL[kcl][c][0];
            bf16x8 bl = *(const bf16x8*)&BlL[kcl][c][0];
#pragma unroll
            for (int mi = 0; mi < 4; mi++) {
                acc[mi][ni] = __builtin_amdgcn_mfma_f32_16x16x32_bf16(ah[mi], bh, acc[mi][ni], 0, 0, 0);
                acc[mi][ni] = __builtin_amdgcn_mfma_f32_16x16x32_bf16(al[mi], bh, acc[mi][ni], 0, 0, 0);
                acc[mi][ni] = __builtin_amdgcn_mfma_f32_16x16x32_bf16(ah[mi], bl, acc[mi][ni], 0, 0, 0);
            }
        }
    }

    // Epilogue. C/D frag layout: col = lane&15, row = (lane>>4)*4 + reg.
    float bval[4];
    if (!bias_row) {
#pragma unroll
        for (int ni = 0; ni < 4; ni++) {
            int col = n0 + wn * 64 + ni * 16 + (lane & 15);
            bval[ni] = bfm ? us2f(((const u16*)bias)[(size_t)e * N + col])
                           : ((const float*)bias)[(size_t)e * N + col];
        }
    }
#pragma unroll
    for (int mi = 0; mi < 4; mi++) {
#pragma unroll
        for (int rg = 0; rg < 4; rg++) {
            int row = m0 + wm * 64 + mi * 16 + (lane >> 4) * 4 + rg;
            if (row >= cnt) continue;
            int tok = lp ? lp[row] : row;
            float brow = 0.f;
            if (bias_row) brow = bfm ? us2f(((const u16*)bias)[(size_t)e * M + row])
                                     : ((const float*)bias)[(size_t)e * M + row];
#pragma unroll
            for (int ni = 0; ni < 4; ni++) {
                int col = n0 + wn * 64 + ni * 16 + (lane & 15);
                float v = acc[mi][ni][rg] + (bias_row ? brow : bval[ni]);
                size_t off = (size_t)tok * N + col;
                if (resid) v += resid[off];
                if (relu) v = fmaxf(v, 0.f);
                if (Cf) {
                    Cf[off] = v;
                } else {
                    u16 hh = f2bf_rn(v);
                    Chi[off] = hh;
                    if (Clo) Clo[off] = f2bf_rn(v - us2f(hh));
                }
            }
        }
    }
}

// ---------------------------------------------------------------------------
// MFMA causal flash attention, SPLIT-bf16 precision (3-term compensation on
// both QK^T and PV — restores R1's ~1e-5 x1 accuracy so MoE routing matches
// the f32 reference; plain-bf16 attention flipped gate argmax for near-tie
// tokens -> O(1) absmax). Q,K row-major hi/lo; V^T hi/lo. One block per
// (64-q tile, b, h); wave = 16 q rows. Swapped QK^T (S^T = K.Q^T).
// Q staged via the P strips, hoisted to regs, strips then reused for P.
// ---------------------------------------------------------------------------
__global__ __launch_bounds__(256) void attn_mfma(
    const u16* __restrict__ qh, const u16* __restrict__ ql,
    const u16* __restrict__ kh, const u16* __restrict__ kl,
    const u16* __restrict__ vth, const u16* __restrict__ vtl,
    u16* __restrict__ ohi, u16* __restrict__ olo)
{
    const int qi = (int)gridDim.x - 1 - (int)blockIdx.x;  // heavy tiles first
    const int bh = blockIdx.y;
    const int b = bh >> 4, h = bh & 15;

    __shared__ __attribute__((aligned(16))) u16 KhL[4096];  // [64 k][64 d] swz
    __shared__ __attribute__((aligned(16))) u16 KlL[4096];
    __shared__ __attribute__((aligned(16))) u16 VhL[4096];  // [64 d][64 k] swz
    __shared__ __attribute__((aligned(16))) u16 VlL[4096];
    __shared__ __attribute__((aligned(16))) u16 PhL[4096];  // Q then P strips
    __shared__ __attribute__((aligned(16))) u16 PlL[4096];

    const int tid = threadIdx.x;
    const int wq = tid >> 6;          // wave id = q-subtile (16 rows)
    const int lane = tid & 63;
    const int l15 = lane & 15, hl = lane >> 4;

    // staging geometry: call covers 8 rows x 128B; row&7 == lane>>3 always
    const int srow = lane >> 3;
    const int sg   = (lane & 7) ^ srow;              // pre-swizzled src granule
    const size_t qk_row = (size_t)D * 2;             // 2048 B
    const size_t vt_row = (size_t)NTOK * 2;          // 8192 B
    const size_t qk_base = (size_t)b * TT * qk_row + (size_t)h * 128;
    const size_t vt_base = (size_t)h * 64 * vt_row + (size_t)(b * TT) * 2;

    // stage Q (hi/lo) into the P strips (wave w -> rows w*16..+15)
    {
        const char* sh = (const char*)qh + qk_base + (size_t)(qi * 64) * qk_row;
        const char* sl = (const char*)ql + qk_base + (size_t)(qi * 64) * qk_row;
#pragma unroll
        for (int c = 0; c < 2; c++) {
            int r = wq * 16 + c * 8 + srow;
            size_t ro = (size_t)r * qk_row + (size_t)(sg * 16);
            GLL16(sh + ro, PhL + wq * 1024 + c * 512);
            GLL16(sl + ro, PlL + wq * 1024 + c * 512);
        }
    }

    float m_reg = -1e30f, l_reg = 0.f;
    f32x4 o[4];
#pragma unroll
    for (int nf = 0; nf < 4; nf++) o[nf] = (f32x4){0.f, 0.f, 0.f, 0.f};

    __syncthreads();
    // hoist Q B-frags (q = wq*16 + l15): hi+lo, 16 VGPRs
    bf16x8 qfh[2], qfl[2];
    {
        const int qrow = wq * 16 + l15;
#pragma unroll
        for (int ks = 0; ks < 2; ks++) {
            int qo = qrow * 64 + (((ks * 4 + hl) ^ (qrow & 7)) * 8);
            qfh[ks] = *(const bf16x8*)(PhL + qo);
            qfl[ks] = *(const bf16x8*)(PlL + qo);
        }
    }

    for (int kt = 0; kt <= qi; kt++) {
        __syncthreads();   // prev tile's LDS reads (and Q hoist) complete
        {
            const char* ksh = (const char*)kh + qk_base + (size_t)(kt * 64) * qk_row;
            const char* ksl = (const char*)kl + qk_base + (size_t)(kt * 64) * qk_row;
            const char* vsh = (const char*)vth + vt_base + (size_t)(kt * 64) * 2;
            const char* vsl = (const char*)vtl + vt_base + (size_t)(kt * 64) * 2;
#pragma unroll
            for (int c = 0; c < 2; c++) {
                int r = wq * 16 + c * 8 + srow;
                size_t ro = (size_t)r * qk_row + (size_t)(sg * 16);
                size_t vo = (size_t)r * vt_row + (size_t)(sg * 16);
                GLL16(ksh + ro, KhL + wq * 1024 + c * 512);
                GLL16(ksl + ro, KlL + wq * 1024 + c * 512);
                GLL16(vsh + vo, VhL + wq * 1024 + c * 512);
                GLL16(vsl + vo, VlL + wq * 1024 + c * 512);
            }
        }
        __syncthreads();

        // S^T = K.Q^T, 3-term split: frag mf = k rows mf*16..+15, cols = 16 q
        f32x4 s[4];
#pragma unroll
        for (int mf = 0; mf < 4; mf++) s[mf] = (f32x4){0.f, 0.f, 0.f, 0.f};
#pragma unroll
        for (int ks = 0; ks < 2; ks++) {
#pragma unroll
            for (int mf = 0; mf < 4; mf++) {
                int row = mf * 16 + l15;
                int go = row * 64 + (((ks * 4 + hl) ^ (row & 7)) * 8);
                bf16x8 kfh = *(const bf16x8*)(KhL + go);
                bf16x8 kfl = *(const bf16x8*)(KlL + go);
                s[mf] = __builtin_amdgcn_mfma_f32_16x16x32_bf16(kfh, qfh[ks], s[mf], 0, 0, 0);
                s[mf] = __builtin_amdgcn_mfma_f32_16x16x32_bf16(kfl, qfh[ks], s[mf], 0, 0, 0);
                s[mf] = __builtin_amdgcn_mfma_f32_16x16x32_bf16(kfh, qfl[ks], s[mf], 0, 0, 0);
            }
        }
        // scale scores by 1/sqrt(DH)
#pragma unroll
        for (int mf = 0; mf < 4; mf++) {
            s[mf][0] *= 0.125f; s[mf][1] *= 0.125f;
            s[mf][2] *= 0.125f; s[mf][3] *= 0.125f;
        }
        // causal mask on diagonal tile: lane holds (k = mf*16+hl*4+r, q = wq*16+l15)
        if (kt == qi) {
            const int ql_ = wq * 16 + l15;
#pragma unroll
            for (int mf = 0; mf < 4; mf++)
#pragma unroll
                for (int r = 0; r < 4; r++)
                    if (mf * 16 + hl * 4 + r > ql_) s[mf][r] = -1e30f;
        }
        // row max: in-lane 16 then across the 4 hl-groups
        float tm = fmaxf(fmaxf(s[0][0], s[0][1]), fmaxf(s[0][2], s[0][3]));
#pragma unroll
        for (int mf = 1; mf < 4; mf++)
            tm = fmaxf(tm, fmaxf(fmaxf(s[mf][0], s[mf][1]), fmaxf(s[mf][2], s[mf][3])));
        tm = fmaxf(tm, __shfl_xor(tm, 16, 64));
        tm = fmaxf(tm, __shfl_xor(tm, 32, 64));
        const float mn = fmaxf(m_reg, tm);
        const float a = (m_reg < -9e29f) ? 0.f : __expf(m_reg - mn);

        // P = exp(S - mn): split hi/lo, write both strips (A-frag layout)
        float ps = 0.f;
#pragma unroll
        for (int mf = 0; mf < 4; mf++) {
            float p0 = __expf(fmaxf(s[mf][0] - mn, -80.f));
            float p1 = __expf(fmaxf(s[mf][1] - mn, -80.f));
            float p2 = __expf(fmaxf(s[mf][2] - mn, -80.f));
            float p3 = __expf(fmaxf(s[mf][3] - mn, -80.f));
            ps += (p0 + p1) + (p2 + p3);
            u16 h0 = f2bf_rn(p0), h1 = f2bf_rn(p1), h2 = f2bf_rn(p2), h3 = f2bf_rn(p3);
            uint2 dh, dl;
            dh.x = ((unsigned)h1 << 16) | h0;
            dh.y = ((unsigned)h3 << 16) | h2;
            dl.x = ((unsigned)f2bf_rn(p1 - us2f(h1)) << 16) | f2bf_rn(p0 - us2f(h0));
            dl.y = ((unsigned)f2bf_rn(p3 - us2f(h3)) << 16) | f2bf_rn(p2 - us2f(h2));
            int kbyte = (mf * 16 + hl * 4) * 2;                 // mult of 8
            int addr = wq * 2048 + l15 * 128 + (kbyte ^ ((l15 & 7) << 4));
            *(uint2*)((char*)PhL + addr) = dh;
            *(uint2*)((char*)PlL + addr) = dl;
        }
        ps += __shfl_xor(ps, 16, 64);
        ps += __shfl_xor(ps, 32, 64);
        l_reg = l_reg * a + ps;
        m_reg = mn;

        // rescale O (rows q = hl*4 + r take a from lane hl*4+r)
        {
            float a0 = __shfl(a, hl * 4 + 0, 64);
            float a1 = __shfl(a, hl * 4 + 1, 64);
            float a2 = __shfl(a, hl * 4 + 2, 64);
            float a3 = __shfl(a, hl * 4 + 3, 64);
#pragma unroll
            for (int nf = 0; nf < 4; nf++) {
                o[nf][0] *= a0; o[nf][1] *= a1; o[nf][2] *= a2; o[nf][3] *= a3;
            }
        }
        // compiler fence: keep P strip reads after the writes
        asm volatile("" ::: "memory");
        // O += P.V, 3-term split (P strips private to this wave)
#pragma unroll
        for (int ks = 0; ks < 2; ks++) {
            int po = wq * 1024 + l15 * 64 + (((ks * 4 + hl) ^ (l15 & 7)) * 8);
            bf16x8 pfh = *(const bf16x8*)(PhL + po);
            bf16x8 pfl = *(const bf16x8*)(PlL + po);
#pragma unroll
            for (int nf = 0; nf < 4; nf++) {
                int vrow = nf * 16 + l15;
                int vo = vrow * 64 + (((ks * 4 + hl) ^ (vrow & 7)) * 8);
                bf16x8 vfh = *(const bf16x8*)(VhL + vo);
                bf16x8 vfl = *(const bf16x8*)(VlL + vo);
                o[nf] = __builtin_amdgcn_mfma_f32_16x16x32_bf16(pfh, vfh, o[nf], 0, 0, 0);
                o[nf] = __builtin_amdgcn_mfma_f32_16x16x32_bf16(pfl, vfh, o[nf], 0, 0, 0);
                o[nf] = __builtin_amdgcn_mfma_f32_16x16x32_bf16(pfh, vfl, o[nf], 0, 0, 0);
            }
        }
    }

    // epilogue: O rows q = hl*4+r; fetch 1/l from lanes hl*4+r; bf16 hi/lo out
    const float linv = 1.f / l_reg;
    float lia[4];
    lia[0] = __shfl(linv, hl * 4 + 0, 64);
    lia[1] = __shfl(linv, hl * 4 + 1, 64);
    lia[2] = __shfl(linv, hl * 4 + 2, 64);
    lia[3] = __shfl(linv, hl * 4 + 3, 64);
    const size_t obase = ((size_t)(b * TT + qi * 64 + wq * 16)) * D + (size_t)h * 64 + l15;
#pragma unroll
    for (int r = 0; r < 4; r++) {
        size_t off = obase + (size_t)(hl * 4 + r) * D;
#pragma unroll
        for (int nf = 0; nf < 4; nf++) {
            float vv = o[nf][r] * lia[r];
            u16 hh = f2bf_rn(vv);
            ohi[off + nf * 16] = hh;
            olo[off + nf * 16] = f2bf_rn(vv - us2f(hh));
        }
    }
}

// ---------------------------------------------------------------------------
// LayerNorm over D=1024 (in-place safe). Residual optionally dual-dtype raw input.
// ---------------------------------------------------------------------------
__global__ __launch_bounds__(256) void layernorm_k(const float* __restrict__ a,
    const void* __restrict__ resid, int rdual, const void* __restrict__ g_,
    const void* __restrict__ b_, float* __restrict__ out,
    const int* __restrict__ meta)
{
    const int bfm = meta[4];
    const int row = blockIdx.x;
    const int tid = threadIdx.x;
    float vals[4];
    float s = 0.f, s2 = 0.f;
#pragma unroll
    for (int i = 0; i < 4; i++) {
        int idx = tid + (i << 8);
        size_t off = (size_t)row * D + idx;
        float v = a[off];
        if (resid) {
            float rv = (rdual && bfm) ? us2f(((const u16*)resid)[off])
                                      : ((const float*)resid)[off];
            v += rv;
        }
        vals[i] = v; s += v; s2 += v * v;
    }
#pragma unroll
    for (int msk = 32; msk > 0; msk >>= 1) {
        s  += __shfl_xor(s,  msk, 64);
        s2 += __shfl_xor(s2, msk, 64);
    }
    __shared__ float red[2][4];
    if ((tid & 63) == 0) { red[0][tid >> 6] = s; red[1][tid >> 6] = s2; }
    __syncthreads();
    s  = red[0][0] + red[0][1] + red[0][2] + red[0][3];
    s2 = red[1][0] + red[1][1] + red[1][2] + red[1][3];
    const float mu = s * (1.f / D);
    const float var = s2 * (1.f / D) - mu * mu;
    const float rs = rsqrtf(var + 1e-5f);
#pragma unroll
    for (int i = 0; i < 4; i++) {
        int idx = tid + (i << 8);
        float gg = bfm ? us2f(((const u16*)g_)[idx]) : ((const float*)g_)[idx];
        float bb = bfm ? us2f(((const u16*)b_)[idx]) : ((const float*)b_)[idx];
        out[(size_t)row * D + idx] = (vals[i] - mu) * rs * gg + bb;
    }
}

// ---------------------------------------------------------------------------
// Top-1 gate in fp32 + bucket scatter. One wave per token.
// ---------------------------------------------------------------------------
__global__ __launch_bounds__(256) void gate_k(const float* __restrict__ x1,
    const void* __restrict__ Wg, const void* __restrict__ bg,
    int* __restrict__ cnt, int* __restrict__ list, const int* __restrict__ meta)
{
    const int bfm = meta[4];
    const int tok = (blockIdx.x * 256 + threadIdx.x) >> 6;
    const int lane = threadIdx.x & 63;
    const float* xr = x1 + (size_t)tok * D;
    float s0 = 0.f, s1 = 0.f, s2 = 0.f, s3 = 0.f;
    for (int d = lane; d < D; d += 64) {
        float xv = xr[d];
        float w0, w1, w2, w3;
        if (bfm) {
            ushort4 wu = ((const ushort4*)Wg)[d];
            w0 = us2f(wu.x); w1 = us2f(wu.y); w2 = us2f(wu.z); w3 = us2f(wu.w);
        } else {
            float4 wf = ((const float4*)Wg)[d];
            w0 = wf.x; w1 = wf.y; w2 = wf.z; w3 = wf.w;
        }
        s0 += xv * w0; s1 += xv * w1; s2 += xv * w2; s3 += xv * w3;
    }
#pragma unroll
    for (int msk = 32; msk > 0; msk >>= 1) {
        s0 += __shfl_xor(s0, msk, 64); s1 += __shfl_xor(s1, msk, 64);
        s2 += __shfl_xor(s2, msk, 64); s3 += __shfl_xor(s3, msk, 64);
    }
    if (lane == 0) {
        float g0, g1, g2, g3;
        if (bfm) {
            g0 = us2f(((const u16*)bg)[0]); g1 = us2f(((const u16*)bg)[1]);
            g2 = us2f(((const u16*)bg)[2]); g3 = us2f(((const u16*)bg)[3]);
        } else {
            g0 = ((const float*)bg)[0]; g1 = ((const float*)bg)[1];
            g2 = ((const float*)bg)[2]; g3 = ((const float*)bg)[3];
        }
        float b0 = s0 + g0, b1 = s1 + g1, b2 = s2 + g2, b3 = s3 + g3;
        int bi = 0; float best = b0;
        if (b1 > best) { best = b1; bi = 1; }
        if (b2 > best) { best = b2; bi = 2; }
        if (b3 > best) { best = b3; bi = 3; }
        int slot = atomicAdd(&cnt[bi], 1);
        list[bi * NTOK + slot] = tok;
    }
}

// ---------------------------------------------------------------------------
extern "C" void kernel_launch(void* const* d_in, const int* in_sizes, int n_in,
                              void* d_out, int out_size, void* d_ws, size_t ws_size,
                              hipStream_t stream)
{
    const void* x  = d_in[0];
    const void* Wq = d_in[2];  const void* bq = d_in[3];
    const void* Wk = d_in[4];  const void* bk = d_in[5];
    const void* Wv = d_in[6];  const void* bv = d_in[7];
    const void* Wo = d_in[8];  const void* bo = d_in[9];
    const void* g1 = d_in[10]; const void* b1 = d_in[11];
    const void* Wg = d_in[12]; const void* bg = d_in[13];
    const void* W1e = d_in[14]; const void* b1e = d_in[15];
    const void* W2e = d_in[16]; const void* b2e = d_in[17];
    const void* g2 = d_in[18]; const void* b2 = d_in[19];

    const size_t NE  = (size_t)NTOK * D;   // 4M elems
    const size_t NE4 = NE * 4;             // bytes per f32 buffer
    char* W = (char*)d_ws;
    float* xf   = (float*)W;
    float* buf0 = (float*)(W + 1 * NE4);
    float* buf1 = (float*)(W + 2 * NE4);
    float* buf2 = (float*)(W + 3 * NE4);
    float* buf3 = (float*)(W + 4 * NE4);
    int* meta = (int*)(W + 5 * NE4);
    int* list = meta + 16;
    u16* xhi = (u16*)(W + 5 * NE4 + (size_t)131072);
    u16* xlo = xhi + NE;
    u16* whi = xlo + NE;
    u16* wlo = whi + (size_t)NTOK * FF;
    u16* qhi = (u16*)buf0;  u16* qlo = qhi + NE;     // Q split [4096][1024]
    u16* khi = (u16*)buf1;  u16* klo = khi + NE;     // K split [4096][1024]
    u16* vthi = (u16*)buf2; u16* vtlo = vthi + NE;   // V^T split [1024][4096]
    u16* ahi = (u16*)buf3;  u16* aloA = ahi + NE;    // attn out split
    u16* hhi = (u16*)buf0;  u16* hlo = hhi + (size_t)NTOK * FF;  // h split
    float* outf = (float*)d_out;

    probe_k<<<1, 64, 0, stream>>>((const unsigned*)x, meta);
    xsplit_k<<<(int)(NE / 4 / 256), 256, 0, stream>>>(x, xhi, xlo, meta);

    const size_t DD = (size_t)D * D;
    wtrans_k<<<dim3(D / 64, D / 64, 1), 256, 0, stream>>>(Wq, whi + 0 * DD, wlo + 0 * DD, D, D, meta);
    wtrans_k<<<dim3(D / 64, D / 64, 1), 256, 0, stream>>>(Wk, whi + 1 * DD, wlo + 1 * DD, D, D, meta);
    wtrans_k<<<dim3(D / 64, D / 64, 1), 256, 0, stream>>>(Wv, whi + 2 * DD, wlo + 2 * DD, D, D, meta);
    wtrans_k<<<dim3(D / 64, D / 64, 1), 256, 0, stream>>>(Wo, whi + 3 * DD, wlo + 3 * DD, D, D, meta);

    // QKV: 3-term split GEMMs with split-bf16 outputs. V via transposed output.
    dim3 gqkv(D / 128, NTOK / 128, 1);
    mgemm_k<3><<<gqkv, 256, 0, stream>>>(xhi, xlo, whi + 0 * DD, wlo + 0 * DD, bq, nullptr,
                                         qhi, qlo, nullptr, nullptr, nullptr, meta, NTOK, D, D, 0, 0);
    mgemm_k<3><<<gqkv, 256, 0, stream>>>(xhi, xlo, whi + 1 * DD, wlo + 1 * DD, bk, nullptr,
                                         khi, klo, nullptr, nullptr, nullptr, meta, NTOK, D, D, 0, 0);
    mgemm_k<3><<<dim3(NTOK / 128, D / 128, 1), 256, 0, stream>>>(whi + 2 * DD, wlo + 2 * DD, xhi, xlo, bv, nullptr,
                                         vthi, vtlo, nullptr, nullptr, nullptr, meta, D, NTOK, D, 0, 1);

    attn_mfma<<<dim3(TT / 64, BSZ * H), 256, 0, stream>>>(qhi, qlo, khi, klo, vthi, vtlo, ahi, aloA);

    mgemm_k<3><<<gqkv, 256, 0, stream>>>(ahi, aloA, whi + 3 * DD, wlo + 3 * DD, bo, buf0,
                                         nullptr, nullptr, nullptr, nullptr, nullptr, meta, NTOK, D, D, 0, 0);
    layernorm_k<<<NTOK, 256, 0, stream>>>(buf0, x, 1, g1, b1, xf, meta);

    gate_k<<<NTOK / 4, 256, 0, stream>>>(xf, Wg, bg, meta, list, meta);
    xsplit_k<<<(int)(NE / 4 / 256), 256, 0, stream>>>(xf, xhi, xlo, nullptr);

    wtrans_k<<<dim3(D / 64, FF / 64, E), 256, 0, stream>>>(W1e, whi, wlo, D, FF, meta);
    mgemm_k<3><<<dim3(FF / 128, NTOK / 128, E), 256, 0, stream>>>(xhi, xlo, whi, wlo, b1e,
                                         nullptr, hhi, hlo, nullptr, list, meta, meta, NTOK, FF, D, 1, 0);

    wtrans_k<<<dim3(FF / 64, D / 64, E), 256, 0, stream>>>(W2e, whi, wlo, FF, D, meta);
    mgemm_k<3><<<dim3(D / 128, NTOK / 128, E), 256, 0, stream>>>(hhi, hlo, whi, wlo, b2e,
                                         outf, nullptr, nullptr, xf, list, meta, meta, NTOK, D, FF, 0, 0);

    layernorm_k<<<NTOK, 256, 0, stream>>>(outf, nullptr, 0, g2, b2, outf, meta);
}

// Round 5
// 1449.510 us; speedup vs baseline: 1.7049x; 1.1490x over previous
//
#include <hip/hip_runtime.h>

// Problem constants (reference file)
#define D   1024
#define H   16
#define DH  64
#define FF  4096
#define E   4
#define BSZ 2
#define TT  2048
#define NTOK (BSZ*TT)   // 4096 tokens

typedef unsigned short u16;
typedef __attribute__((ext_vector_type(8))) short bf16x8;   // 8 bf16 = 4 VGPRs (MFMA A/B frag)
typedef __attribute__((ext_vector_type(4))) float f32x4;    // MFMA C/D frag

__device__ __forceinline__ float us2f(u16 u) {
    return __uint_as_float(((unsigned int)u) << 16);  // bf16 -> f32 exact
}
__device__ __forceinline__ u16 f2bf_rn(float f) {     // f32 -> bf16 round-to-nearest-even
    unsigned u = __float_as_uint(f);
    return (u16)((u + 0x7FFFu + ((u >> 16) & 1u)) >> 16);
}

// async global->LDS, 16B per lane; LDS dest = wave-uniform base + lane*16
#define GLL16(gsrc, ldst) \
    __builtin_amdgcn_global_load_lds((const __attribute__((address_space(1))) void*)(gsrc), \
                                     (__attribute__((address_space(3))) void*)(ldst), 16, 0, 0)

// ---------------------------------------------------------------------------
// Dtype probe. Zero-inits expert counters.
// ---------------------------------------------------------------------------
__global__ __launch_bounds__(64) void probe_k(const unsigned* __restrict__ xw,
                                              int* __restrict__ meta) {
    const int lane = threadIdx.x;
    int wild = 0;
    for (int i = 0; i < 32; i++) {
        unsigned u = xw[lane * 32 + i];
        unsigned lo = u & 0xFFFFu;
        if ((lo & 0x7F80u) >= 0x5A00u) wild++;
    }
#pragma unroll
    for (int m = 32; m > 0; m >>= 1) wild += __shfl_xor(wild, m, 64);
    if (lane == 0) meta[4] = (wild < 64) ? 1 : 0;   // 1 = bf16 inputs, 0 = f32
    if (lane < 4) meta[lane] = 0;                   // expert counters
}

// ---------------------------------------------------------------------------
// Split a tensor into bf16 hi/lo pair (hi = rn(v), lo = rn(v - hi)).
// ---------------------------------------------------------------------------
__global__ __launch_bounds__(256) void xsplit_k(const void* __restrict__ in,
    u16* __restrict__ hi, u16* __restrict__ lo, const int* __restrict__ meta)
{
    const int i = blockIdx.x * 256 + threadIdx.x;
    float4 v;
    if (meta && meta[4]) {
        ushort4 u = ((const ushort4*)in)[i];
        v = make_float4(us2f(u.x), us2f(u.y), us2f(u.z), us2f(u.w));
    } else {
        v = ((const float4*)in)[i];
    }
    ushort4 h, l;
    h.x = f2bf_rn(v.x); l.x = f2bf_rn(v.x - us2f(h.x));
    h.y = f2bf_rn(v.y); l.y = f2bf_rn(v.y - us2f(h.y));
    h.z = f2bf_rn(v.z); l.z = f2bf_rn(v.z - us2f(h.z));
    h.w = f2bf_rn(v.w); l.w = f2bf_rn(v.w - us2f(h.w));
    ((ushort4*)hi)[i] = h;
    ((ushort4*)lo)[i] = l;
}

// ---------------------------------------------------------------------------
// Weight transpose + bf16 split: W[e][K][N] (dual dtype) -> T{hi,lo}[e][N][K].
// ---------------------------------------------------------------------------
__global__ __launch_bounds__(256) void wtrans_k(const void* __restrict__ Wsrc,
    u16* __restrict__ Thi, u16* __restrict__ Tlo,
    int K, int N, const int* __restrict__ meta)
{
    const int bfm = meta[4];
    const int e = blockIdx.z;
    const int k0 = blockIdx.x * 64, n0 = blockIdx.y * 64;
    __shared__ float t[64][65];
    const int tid = threadIdx.x;
    const size_t sbase = (size_t)e * K * N;
#pragma unroll
    for (int rr = 0; rr < 4; rr++) {
        int row = rr * 16 + (tid >> 4);      // k
        int c4  = (tid & 15) * 4;            // n
        size_t off = sbase + (size_t)(k0 + row) * N + n0 + c4;
        float4 v;
        if (bfm) {
            ushort4 u = *(const ushort4*)((const u16*)Wsrc + off);
            v = make_float4(us2f(u.x), us2f(u.y), us2f(u.z), us2f(u.w));
        } else {
            v = *(const float4*)((const float*)Wsrc + off);
        }
        t[row][c4 + 0] = v.x; t[row][c4 + 1] = v.y;
        t[row][c4 + 2] = v.z; t[row][c4 + 3] = v.w;
    }
    __syncthreads();
    const size_t dbase = (size_t)e * K * N;  // transposed [N][K]
#pragma unroll
    for (int rr = 0; rr < 4; rr++) {
        int nrow = rr * 16 + (tid >> 4);
        int k4   = (tid & 15) * 4;
        ushort4 h, l;
        float f0 = t[k4 + 0][nrow], f1 = t[k4 + 1][nrow];
        float f2 = t[k4 + 2][nrow], f3 = t[k4 + 3][nrow];
        h.x = f2bf_rn(f0); l.x = f2bf_rn(f0 - us2f(h.x));
        h.y = f2bf_rn(f1); l.y = f2bf_rn(f1 - us2f(h.y));
        h.z = f2bf_rn(f2); l.z = f2bf_rn(f2 - us2f(h.z));
        h.w = f2bf_rn(f3); l.w = f2bf_rn(f3 - us2f(h.w));
        size_t doff = dbase + (size_t)(n0 + nrow) * K + k0 + k4;
        *(ushort4*)&Thi[doff] = h;
        *(ushort4*)&Tlo[doff] = l;
    }
}

// ---------------------------------------------------------------------------
// MFMA GEMM, split-bf16 (Ahi+Alo)(Bhi+Blo) 3-term compensation.
//   C[M,N] = A[M,K] * B^T[N,K] + bias; 128x128 tile, BK=32, 4 waves.
//   NEW (R5): 2-phase double-buffered LDS pipeline (stage t+1 issued before
//   compute t; ONE barrier per K-step -> load latency hides under MFMA) and
//   XCD-chunked bijective block swizzle (swz=1: n-chunk for big-B GEMMs,
//   swz=2: m-chunk for big-A GEMMs) for per-XCD L2 panel reuse.
// ---------------------------------------------------------------------------
__global__ __launch_bounds__(256) void mgemm_k(
    const u16* __restrict__ Ahi, const u16* __restrict__ Alo,
    const u16* __restrict__ Bhi, const u16* __restrict__ Blo,   // [e][N][K]
    const void* __restrict__ bias,                              // dual dtype
    float* __restrict__ Cf,                                     // f32 out (or null)
    u16* __restrict__ Chi, u16* __restrict__ Clo,               // bf16 out (Clo opt)
    const float* __restrict__ resid,
    const int* __restrict__ rowlist, const int* __restrict__ rowcnt,
    const int* __restrict__ meta, int M, int N, int K, int relu, int bias_row,
    int swz)
{
    const int bfm = meta[4];
    const int e = blockIdx.z;
    const int cnt = rowcnt ? rowcnt[e] : M;

    // XCD-chunked swizzle (bijective; dispatch order approx round-robins XCDs)
    int bx = blockIdx.x, by = blockIdx.y;
    {
        const int gx = gridDim.x, gy = gridDim.y;
        int f = bx + gx * by;
        if (swz == 1 && (gx & 7) == 0) {           // n-chunk: XCD owns n-band
            int bandw = gx >> 3;
            int xcd = f & 7, r = f >> 3;
            bx = xcd * bandw + (r % bandw);
            by = r / bandw;
        } else if (swz == 2 && (gy & 7) == 0) {    // m-chunk: XCD owns m-band
            int bandh = gy >> 3;
            int xcd = f & 7, r = f >> 3;
            by = xcd * bandh + (r % bandh);
            bx = r / bandh;
        }
    }
    const int m0 = by * 128;
    if (m0 >= cnt) return;
    const int n0 = bx * 128;
    const int* lp = rowlist ? (rowlist + e * NTOK) : nullptr;

    // [dbuf][arr: 0=Ahi 1=Alo 2=Bhi 3=Blo][kc][row][8] : 2 x 32KB = 64KB
    __shared__ __attribute__((aligned(16))) u16 Ls[2][4][4][128][8];

    const int tid = threadIdx.x;
    const int wave = tid >> 6, lane = tid & 63;
    const int wm = wave >> 1, wn = wave & 1;

    // Per-wave staging: w0=Ahi, w1=Alo, w2=Bhi, w3=Blo (8 GLL16 each)
    const char* sptr;
    size_t soff0 = 0, soff1 = 0;
    if (wave < 2) {
        int r0 = m0 + lane;      if (r0 >= cnt) r0 = cnt - 1;
        int r1 = m0 + 64 + lane; if (r1 >= cnt) r1 = cnt - 1;
        int t0 = lp ? lp[r0] : r0;
        int t1 = lp ? lp[r1] : r1;
        sptr  = (const char*)(wave ? Alo : Ahi);
        soff0 = (size_t)t0 * K * 2;
        soff1 = (size_t)t1 * K * 2;
    } else {
        sptr  = (const char*)(((wave == 3) ? Blo : Bhi) + (size_t)e * N * K);
        soff0 = (size_t)(n0 + lane) * K * 2;
        soff1 = (size_t)(n0 + 64 + lane) * K * 2;
    }

    f32x4 acc[4][4];
#pragma unroll
    for (int mi = 0; mi < 4; mi++)
#pragma unroll
        for (int ni = 0; ni < 4; ni++) acc[mi][ni] = (f32x4){0.f, 0.f, 0.f, 0.f};

    const int lrow = lane & 15, kcl = lane >> 4;

#define MG_STAGE(buf, kb) do {                                               \
        u16* db = &Ls[buf][wave][0][0][0];                                   \
        _Pragma("unroll")                                                    \
        for (int kc = 0; kc < 4; kc++) {                                     \
            GLL16(sptr + soff0 + (kb) + kc * 16, db + kc * 1024);            \
            GLL16(sptr + soff1 + (kb) + kc * 16, db + kc * 1024 + 512);      \
        }                                                                    \
    } while (0)

    MG_STAGE(0, 0);                         // prologue: stage tile 0
    int cur = 0;
    for (int k0 = 0; k0 < K; k0 += 32) {
        __syncthreads();                    // drains vmcnt: buf[cur] ready; prev reads done
        if (k0 + 32 < K) MG_STAGE(cur ^ 1, (size_t)(k0 + 32) * 2);  // prefetch next
        bf16x8 ah[4], al[4];
#pragma unroll
        for (int mi = 0; mi < 4; mi++) {
            int r = wm * 64 + mi * 16 + lrow;
            ah[mi] = *(const bf16x8*)&Ls[cur][0][kcl][r][0];
            al[mi] = *(const bf16x8*)&Ls[cur][1][kcl][r][0];
        }
#pragma unroll
        for (int ni = 0; ni < 4; ni++) {
            int c = wn * 64 + ni * 16 + lrow;
            bf16x8 bh = *(const bf16x8*)&Ls[cur][2][kcl][c][0];
            bf16x8 bl = *(const bf16x8*)&Ls[cur][3][kcl][c][0];
#pragma unroll
            for (int mi = 0; mi < 4; mi++) {
                acc[mi][ni] = __builtin_amdgcn_mfma_f32_16x16x32_bf16(ah[mi], bh, acc[mi][ni], 0, 0, 0);
                acc[mi][ni] = __builtin_amdgcn_mfma_f32_16x16x32_bf16(al[mi], bh, acc[mi][ni], 0, 0, 0);
                acc[mi][ni] = __builtin_amdgcn_mfma_f32_16x16x32_bf16(ah[mi], bl, acc[mi][ni], 0, 0, 0);
            }
        }
        cur ^= 1;
    }
#undef MG_STAGE

    // Epilogue. C/D frag layout: col = lane&15, row = (lane>>4)*4 + reg.
    float bval[4];
    if (!bias_row) {
#pragma unroll
        for (int ni = 0; ni < 4; ni++) {
            int col = n0 + wn * 64 + ni * 16 + (lane & 15);
            bval[ni] = bfm ? us2f(((const u16*)bias)[(size_t)e * N + col])
                           : ((const float*)bias)[(size_t)e * N + col];
        }
    }
#pragma unroll
    for (int mi = 0; mi < 4; mi++) {
#pragma unroll
        for (int rg = 0; rg < 4; rg++) {
            int row = m0 + wm * 64 + mi * 16 + (lane >> 4) * 4 + rg;
            if (row >= cnt) continue;
            int tok = lp ? lp[row] : row;
            float brow = 0.f;
            if (bias_row) brow = bfm ? us2f(((const u16*)bias)[(size_t)e * M + row])
                                     : ((const float*)bias)[(size_t)e * M + row];
#pragma unroll
            for (int ni = 0; ni < 4; ni++) {
                int col = n0 + wn * 64 + ni * 16 + (lane & 15);
                float v = acc[mi][ni][rg] + (bias_row ? brow : bval[ni]);
                size_t off = (size_t)tok * N + col;
                if (resid) v += resid[off];
                if (relu) v = fmaxf(v, 0.f);
                if (Cf) {
                    Cf[off] = v;
                } else {
                    u16 hh = f2bf_rn(v);
                    Chi[off] = hh;
                    if (Clo) Clo[off] = f2bf_rn(v - us2f(hh));
                }
            }
        }
    }
}

// ---------------------------------------------------------------------------
// MFMA causal flash attention, SPLIT-bf16 precision (3-term on QK^T and PV).
// R5: bh-chunked XCD swizzle (each XCD owns 4 heads -> K/V panel L2-hot).
// Numerics identical to the R4-passing version.
// ---------------------------------------------------------------------------
__global__ __launch_bounds__(256) void attn_mfma(
    const u16* __restrict__ qh, const u16* __restrict__ ql,
    const u16* __restrict__ kh, const u16* __restrict__ kl,
    const u16* __restrict__ vth, const u16* __restrict__ vtl,
    u16* __restrict__ ohi, u16* __restrict__ olo)
{
    // swizzle: f = bx + 32*by; XCD owns a 4-wide bh band, sweeping q-tiles
    int bx = blockIdx.x, by = blockIdx.y;
    {
        int f = bx + (int)gridDim.x * by;
        int xcd = f & 7, r = f >> 3;
        const int bandh = (int)gridDim.y >> 3;          // 4
        by = xcd * bandh + (r % bandh);
        bx = r / bandh;
    }
    const int qi = (int)gridDim.x - 1 - bx;  // heavy tiles first
    const int bh = by;
    const int b = bh >> 4, h = bh & 15;

    __shared__ __attribute__((aligned(16))) u16 KhL[4096];  // [64 k][64 d] swz
    __shared__ __attribute__((aligned(16))) u16 KlL[4096];
    __shared__ __attribute__((aligned(16))) u16 VhL[4096];  // [64 d][64 k] swz
    __shared__ __attribute__((aligned(16))) u16 VlL[4096];
    __shared__ __attribute__((aligned(16))) u16 PhL[4096];  // Q then P strips
    __shared__ __attribute__((aligned(16))) u16 PlL[4096];

    const int tid = threadIdx.x;
    const int wq = tid >> 6;          // wave id = q-subtile (16 rows)
    const int lane = tid & 63;
    const int l15 = lane & 15, hl = lane >> 4;

    // staging geometry: call covers 8 rows x 128B; row&7 == lane>>3 always
    const int srow = lane >> 3;
    const int sg   = (lane & 7) ^ srow;              // pre-swizzled src granule
    const size_t qk_row = (size_t)D * 2;             // 2048 B
    const size_t vt_row = (size_t)NTOK * 2;          // 8192 B
    const size_t qk_base = (size_t)b * TT * qk_row + (size_t)h * 128;
    const size_t vt_base = (size_t)h * 64 * vt_row + (size_t)(b * TT) * 2;

    // stage Q (hi/lo) into the P strips (wave w -> rows w*16..+15)
    {
        const char* sh = (const char*)qh + qk_base + (size_t)(qi * 64) * qk_row;
        const char* sl = (const char*)ql + qk_base + (size_t)(qi * 64) * qk_row;
#pragma unroll
        for (int c = 0; c < 2; c++) {
            int r = wq * 16 + c * 8 + srow;
            size_t ro = (size_t)r * qk_row + (size_t)(sg * 16);
            GLL16(sh + ro, PhL + wq * 1024 + c * 512);
            GLL16(sl + ro, PlL + wq * 1024 + c * 512);
        }
    }

    float m_reg = -1e30f, l_reg = 0.f;
    f32x4 o[4];
#pragma unroll
    for (int nf = 0; nf < 4; nf++) o[nf] = (f32x4){0.f, 0.f, 0.f, 0.f};

    __syncthreads();
    // hoist Q B-frags (q = wq*16 + l15): hi+lo, 16 VGPRs
    bf16x8 qfh[2], qfl[2];
    {
        const int qrow = wq * 16 + l15;
#pragma unroll
        for (int ks = 0; ks < 2; ks++) {
            int qo = qrow * 64 + (((ks * 4 + hl) ^ (qrow & 7)) * 8);
            qfh[ks] = *(const bf16x8*)(PhL + qo);
            qfl[ks] = *(const bf16x8*)(PlL + qo);
        }
    }

    for (int kt = 0; kt <= qi; kt++) {
        __syncthreads();   // prev tile's LDS reads (and Q hoist) complete
        {
            const char* ksh = (const char*)kh + qk_base + (size_t)(kt * 64) * qk_row;
            const char* ksl = (const char*)kl + qk_base + (size_t)(kt * 64) * qk_row;
            const char* vsh = (const char*)vth + vt_base + (size_t)(kt * 64) * 2;
            const char* vsl = (const char*)vtl + vt_base + (size_t)(kt * 64) * 2;
#pragma unroll
            for (int c = 0; c < 2; c++) {
                int r = wq * 16 + c * 8 + srow;
                size_t ro = (size_t)r * qk_row + (size_t)(sg * 16);
                size_t vo = (size_t)r * vt_row + (size_t)(sg * 16);
                GLL16(ksh + ro, KhL + wq * 1024 + c * 512);
                GLL16(ksl + ro, KlL + wq * 1024 + c * 512);
                GLL16(vsh + vo, VhL + wq * 1024 + c * 512);
                GLL16(vsl + vo, VlL + wq * 1024 + c * 512);
            }
        }
        __syncthreads();

        // S^T = K.Q^T, 3-term split: frag mf = k rows mf*16..+15, cols = 16 q
        f32x4 s[4];
#pragma unroll
        for (int mf = 0; mf < 4; mf++) s[mf] = (f32x4){0.f, 0.f, 0.f, 0.f};
#pragma unroll
        for (int ks = 0; ks < 2; ks++) {
#pragma unroll
            for (int mf = 0; mf < 4; mf++) {
                int row = mf * 16 + l15;
                int go = row * 64 + (((ks * 4 + hl) ^ (row & 7)) * 8);
                bf16x8 kfh = *(const bf16x8*)(KhL + go);
                bf16x8 kfl = *(const bf16x8*)(KlL + go);
                s[mf] = __builtin_amdgcn_mfma_f32_16x16x32_bf16(kfh, qfh[ks], s[mf], 0, 0, 0);
                s[mf] = __builtin_amdgcn_mfma_f32_16x16x32_bf16(kfl, qfh[ks], s[mf], 0, 0, 0);
                s[mf] = __builtin_amdgcn_mfma_f32_16x16x32_bf16(kfh, qfl[ks], s[mf], 0, 0, 0);
            }
        }
        // scale scores by 1/sqrt(DH)
#pragma unroll
        for (int mf = 0; mf < 4; mf++) {
            s[mf][0] *= 0.125f; s[mf][1] *= 0.125f;
            s[mf][2] *= 0.125f; s[mf][3] *= 0.125f;
        }
        // causal mask on diagonal tile: lane holds (k = mf*16+hl*4+r, q = wq*16+l15)
        if (kt == qi) {
            const int ql_ = wq * 16 + l15;
#pragma unroll
            for (int mf = 0; mf < 4; mf++)
#pragma unroll
                for (int r = 0; r < 4; r++)
                    if (mf * 16 + hl * 4 + r > ql_) s[mf][r] = -1e30f;
        }
        // row max: in-lane 16 then across the 4 hl-groups
        float tm = fmaxf(fmaxf(s[0][0], s[0][1]), fmaxf(s[0][2], s[0][3]));
#pragma unroll
        for (int mf = 1; mf < 4; mf++)
            tm = fmaxf(tm, fmaxf(fmaxf(s[mf][0], s[mf][1]), fmaxf(s[mf][2], s[mf][3])));
        tm = fmaxf(tm, __shfl_xor(tm, 16, 64));
        tm = fmaxf(tm, __shfl_xor(tm, 32, 64));
        const float mn = fmaxf(m_reg, tm);
        const float a = (m_reg < -9e29f) ? 0.f : __expf(m_reg - mn);

        // P = exp(S - mn): split hi/lo, write both strips (A-frag layout)
        float ps = 0.f;
#pragma unroll
        for (int mf = 0; mf < 4; mf++) {
            float p0 = __expf(fmaxf(s[mf][0] - mn, -80.f));
            float p1 = __expf(fmaxf(s[mf][1] - mn, -80.f));
            float p2 = __expf(fmaxf(s[mf][2] - mn, -80.f));
            float p3 = __expf(fmaxf(s[mf][3] - mn, -80.f));
            ps += (p0 + p1) + (p2 + p3);
            u16 h0 = f2bf_rn(p0), h1 = f2bf_rn(p1), h2 = f2bf_rn(p2), h3 = f2bf_rn(p3);
            uint2 dh, dl;
            dh.x = ((unsigned)h1 << 16) | h0;
            dh.y = ((unsigned)h3 << 16) | h2;
            dl.x = ((unsigned)f2bf_rn(p1 - us2f(h1)) << 16) | f2bf_rn(p0 - us2f(h0));
            dl.y = ((unsigned)f2bf_rn(p3 - us2f(h3)) << 16) | f2bf_rn(p2 - us2f(h2));
            int kbyte = (mf * 16 + hl * 4) * 2;                 // mult of 8
            int addr = wq * 2048 + l15 * 128 + (kbyte ^ ((l15 & 7) << 4));
            *(uint2*)((char*)PhL + addr) = dh;
            *(uint2*)((char*)PlL + addr) = dl;
        }
        ps += __shfl_xor(ps, 16, 64);
        ps += __shfl_xor(ps, 32, 64);
        l_reg = l_reg * a + ps;
        m_reg = mn;

        // rescale O (rows q = hl*4 + r take a from lane hl*4+r)
        {
            float a0 = __shfl(a, hl * 4 + 0, 64);
            float a1 = __shfl(a, hl * 4 + 1, 64);
            float a2 = __shfl(a, hl * 4 + 2, 64);
            float a3 = __shfl(a, hl * 4 + 3, 64);
#pragma unroll
            for (int nf = 0; nf < 4; nf++) {
                o[nf][0] *= a0; o[nf][1] *= a1; o[nf][2] *= a2; o[nf][3] *= a3;
            }
        }
        // compiler fence: keep P strip reads after the writes
        asm volatile("" ::: "memory");
        // O += P.V, 3-term split (P strips private to this wave)
#pragma unroll
        for (int ks = 0; ks < 2; ks++) {
            int po = wq * 1024 + l15 * 64 + (((ks * 4 + hl) ^ (l15 & 7)) * 8);
            bf16x8 pfh = *(const bf16x8*)(PhL + po);
            bf16x8 pfl = *(const bf16x8*)(PlL + po);
#pragma unroll
            for (int nf = 0; nf < 4; nf++) {
                int vrow = nf * 16 + l15;
                int vo = vrow * 64 + (((ks * 4 + hl) ^ (vrow & 7)) * 8);
                bf16x8 vfh = *(const bf16x8*)(VhL + vo);
                bf16x8 vfl = *(const bf16x8*)(VlL + vo);
                o[nf] = __builtin_amdgcn_mfma_f32_16x16x32_bf16(pfh, vfh, o[nf], 0, 0, 0);
                o[nf] = __builtin_amdgcn_mfma_f32_16x16x32_bf16(pfl, vfh, o[nf], 0, 0, 0);
                o[nf] = __builtin_amdgcn_mfma_f32_16x16x32_bf16(pfh, vfl, o[nf], 0, 0, 0);
            }
        }
    }

    // epilogue: O rows q = hl*4+r; fetch 1/l from lanes hl*4+r; bf16 hi/lo out
    const float linv = 1.f / l_reg;
    float lia[4];
    lia[0] = __shfl(linv, hl * 4 + 0, 64);
    lia[1] = __shfl(linv, hl * 4 + 1, 64);
    lia[2] = __shfl(linv, hl * 4 + 2, 64);
    lia[3] = __shfl(linv, hl * 4 + 3, 64);
    const size_t obase = ((size_t)(b * TT + qi * 64 + wq * 16)) * D + (size_t)h * 64 + l15;
#pragma unroll
    for (int r = 0; r < 4; r++) {
        size_t off = obase + (size_t)(hl * 4 + r) * D;
#pragma unroll
        for (int nf = 0; nf < 4; nf++) {
            float vv = o[nf][r] * lia[r];
            u16 hh = f2bf_rn(vv);
            ohi[off + nf * 16] = hh;
            olo[off + nf * 16] = f2bf_rn(vv - us2f(hh));
        }
    }
}

// ---------------------------------------------------------------------------
// LayerNorm over D=1024 (in-place safe). Residual optionally dual-dtype raw input.
// ---------------------------------------------------------------------------
__global__ __launch_bounds__(256) void layernorm_k(const float* __restrict__ a,
    const void* __restrict__ resid, int rdual, const void* __restrict__ g_,
    const void* __restrict__ b_, float* __restrict__ out,
    const int* __restrict__ meta)
{
    const int bfm = meta[4];
    const int row = blockIdx.x;
    const int tid = threadIdx.x;
    float vals[4];
    float s = 0.f, s2 = 0.f;
#pragma unroll
    for (int i = 0; i < 4; i++) {
        int idx = tid + (i << 8);
        size_t off = (size_t)row * D + idx;
        float v = a[off];
        if (resid) {
            float rv = (rdual && bfm) ? us2f(((const u16*)resid)[off])
                                      : ((const float*)resid)[off];
            v += rv;
        }
        vals[i] = v; s += v; s2 += v * v;
    }
#pragma unroll
    for (int msk = 32; msk > 0; msk >>= 1) {
        s  += __shfl_xor(s,  msk, 64);
        s2 += __shfl_xor(s2, msk, 64);
    }
    __shared__ float red[2][4];
    if ((tid & 63) == 0) { red[0][tid >> 6] = s; red[1][tid >> 6] = s2; }
    __syncthreads();
    s  = red[0][0] + red[0][1] + red[0][2] + red[0][3];
    s2 = red[1][0] + red[1][1] + red[1][2] + red[1][3];
    const float mu = s * (1.f / D);
    const float var = s2 * (1.f / D) - mu * mu;
    const float rs = rsqrtf(var + 1e-5f);
#pragma unroll
    for (int i = 0; i < 4; i++) {
        int idx = tid + (i << 8);
        float gg = bfm ? us2f(((const u16*)g_)[idx]) : ((const float*)g_)[idx];
        float bb = bfm ? us2f(((const u16*)b_)[idx]) : ((const float*)b_)[idx];
        out[(size_t)row * D + idx] = (vals[i] - mu) * rs * gg + bb;
    }
}

// ---------------------------------------------------------------------------
// Top-1 gate in fp32 + bucket scatter. One wave per token.
// ---------------------------------------------------------------------------
__global__ __launch_bounds__(256) void gate_k(const float* __restrict__ x1,
    const void* __restrict__ Wg, const void* __restrict__ bg,
    int* __restrict__ cnt, int* __restrict__ list, const int* __restrict__ meta)
{
    const int bfm = meta[4];
    const int tok = (blockIdx.x * 256 + threadIdx.x) >> 6;
    const int lane = threadIdx.x & 63;
    const float* xr = x1 + (size_t)tok * D;
    float s0 = 0.f, s1 = 0.f, s2 = 0.f, s3 = 0.f;
    for (int d = lane; d < D; d += 64) {
        float xv = xr[d];
        float w0, w1, w2, w3;
        if (bfm) {
            ushort4 wu = ((const ushort4*)Wg)[d];
            w0 = us2f(wu.x); w1 = us2f(wu.y); w2 = us2f(wu.z); w3 = us2f(wu.w);
        } else {
            float4 wf = ((const float4*)Wg)[d];
            w0 = wf.x; w1 = wf.y; w2 = wf.z; w3 = wf.w;
        }
        s0 += xv * w0; s1 += xv * w1; s2 += xv * w2; s3 += xv * w3;
    }
#pragma unroll
    for (int msk = 32; msk > 0; msk >>= 1) {
        s0 += __shfl_xor(s0, msk, 64); s1 += __shfl_xor(s1, msk, 64);
        s2 += __shfl_xor(s2, msk, 64); s3 += __shfl_xor(s3, msk, 64);
    }
    if (lane == 0) {
        float g0, g1, g2, g3;
        if (bfm) {
            g0 = us2f(((const u16*)bg)[0]); g1 = us2f(((const u16*)bg)[1]);
            g2 = us2f(((const u16*)bg)[2]); g3 = us2f(((const u16*)bg)[3]);
        } else {
            g0 = ((const float*)bg)[0]; g1 = ((const float*)bg)[1];
            g2 = ((const float*)bg)[2]; g3 = ((const float*)bg)[3];
        }
        float b0 = s0 + g0, b1 = s1 + g1, b2 = s2 + g2, b3 = s3 + g3;
        int bi = 0; float best = b0;
        if (b1 > best) { best = b1; bi = 1; }
        if (b2 > best) { best = b2; bi = 2; }
        if (b3 > best) { best = b3; bi = 3; }
        int slot = atomicAdd(&cnt[bi], 1);
        list[bi * NTOK + slot] = tok;
    }
}

// ---------------------------------------------------------------------------
extern "C" void kernel_launch(void* const* d_in, const int* in_sizes, int n_in,
                              void* d_out, int out_size, void* d_ws, size_t ws_size,
                              hipStream_t stream)
{
    const void* x  = d_in[0];
    const void* Wq = d_in[2];  const void* bq = d_in[3];
    const void* Wk = d_in[4];  const void* bk = d_in[5];
    const void* Wv = d_in[6];  const void* bv = d_in[7];
    const void* Wo = d_in[8];  const void* bo = d_in[9];
    const void* g1 = d_in[10]; const void* b1 = d_in[11];
    const void* Wg = d_in[12]; const void* bg = d_in[13];
    const void* W1e = d_in[14]; const void* b1e = d_in[15];
    const void* W2e = d_in[16]; const void* b2e = d_in[17];
    const void* g2 = d_in[18]; const void* b2 = d_in[19];

    const size_t NE  = (size_t)NTOK * D;   // 4M elems
    const size_t NE4 = NE * 4;             // bytes per f32 buffer
    char* W = (char*)d_ws;
    float* xf   = (float*)W;
    float* buf0 = (float*)(W + 1 * NE4);
    float* buf1 = (float*)(W + 2 * NE4);
    float* buf2 = (float*)(W + 3 * NE4);
    float* buf3 = (float*)(W + 4 * NE4);
    int* meta = (int*)(W + 5 * NE4);
    int* list = meta + 16;
    u16* xhi = (u16*)(W + 5 * NE4 + (size_t)131072);
    u16* xlo = xhi + NE;
    u16* whi = xlo + NE;
    u16* wlo = whi + (size_t)NTOK * FF;
    u16* qhi = (u16*)buf0;  u16* qlo = qhi + NE;     // Q split [4096][1024]
    u16* khi = (u16*)buf1;  u16* klo = khi + NE;     // K split [4096][1024]
    u16* vthi = (u16*)buf2; u16* vtlo = vthi + NE;   // V^T split [1024][4096]
    u16* ahi = (u16*)buf3;  u16* aloA = ahi + NE;    // attn out split
    u16* hhi = (u16*)buf0;  u16* hlo = hhi + (size_t)NTOK * FF;  // h split
    float* outf = (float*)d_out;

    probe_k<<<1, 64, 0, stream>>>((const unsigned*)x, meta);
    xsplit_k<<<(int)(NE / 4 / 256), 256, 0, stream>>>(x, xhi, xlo, meta);

    const size_t DD = (size_t)D * D;
    wtrans_k<<<dim3(D / 64, D / 64, 1), 256, 0, stream>>>(Wq, whi + 0 * DD, wlo + 0 * DD, D, D, meta);
    wtrans_k<<<dim3(D / 64, D / 64, 1), 256, 0, stream>>>(Wk, whi + 1 * DD, wlo + 1 * DD, D, D, meta);
    wtrans_k<<<dim3(D / 64, D / 64, 1), 256, 0, stream>>>(Wv, whi + 2 * DD, wlo + 2 * DD, D, D, meta);
    wtrans_k<<<dim3(D / 64, D / 64, 1), 256, 0, stream>>>(Wo, whi + 3 * DD, wlo + 3 * DD, D, D, meta);

    // QKV: 3-term split GEMMs with split-bf16 outputs. V via transposed output.
    // swz: 2 = m-chunk (A is big operand), 1 = n-chunk (B is big operand).
    dim3 gqkv(D / 128, NTOK / 128, 1);
    mgemm_k<<<gqkv, 256, 0, stream>>>(xhi, xlo, whi + 0 * DD, wlo + 0 * DD, bq, nullptr,
                                      qhi, qlo, nullptr, nullptr, nullptr, meta, NTOK, D, D, 0, 0, 2);
    mgemm_k<<<gqkv, 256, 0, stream>>>(xhi, xlo, whi + 1 * DD, wlo + 1 * DD, bk, nullptr,
                                      khi, klo, nullptr, nullptr, nullptr, meta, NTOK, D, D, 0, 0, 2);
    mgemm_k<<<dim3(NTOK / 128, D / 128, 1), 256, 0, stream>>>(whi + 2 * DD, wlo + 2 * DD, xhi, xlo, bv, nullptr,
                                      vthi, vtlo, nullptr, nullptr, nullptr, meta, D, NTOK, D, 0, 1, 1);

    attn_mfma<<<dim3(TT / 64, BSZ * H), 256, 0, stream>>>(qhi, qlo, khi, klo, vthi, vtlo, ahi, aloA);

    mgemm_k<<<gqkv, 256, 0, stream>>>(ahi, aloA, whi + 3 * DD, wlo + 3 * DD, bo, buf0,
                                      nullptr, nullptr, nullptr, nullptr, nullptr, meta, NTOK, D, D, 0, 0, 2);
    layernorm_k<<<NTOK, 256, 0, stream>>>(buf0, x, 1, g1, b1, xf, meta);

    gate_k<<<NTOK / 4, 256, 0, stream>>>(xf, Wg, bg, meta, list, meta);
    xsplit_k<<<(int)(NE / 4 / 256), 256, 0, stream>>>(xf, xhi, xlo, nullptr);

    wtrans_k<<<dim3(D / 64, FF / 64, E), 256, 0, stream>>>(W1e, whi, wlo, D, FF, meta);
    mgemm_k<<<dim3(FF / 128, NTOK / 128, E), 256, 0, stream>>>(xhi, xlo, whi, wlo, b1e,
                                      nullptr, hhi, hlo, nullptr, list, meta, meta, NTOK, FF, D, 1, 0, 1);

    wtrans_k<<<dim3(FF / 64, D / 64, E), 256, 0, stream>>>(W2e, whi, wlo, FF, D, meta);
    mgemm_k<<<dim3(D / 128, NTOK / 128, E), 256, 0, stream>>>(hhi, hlo, whi, wlo, b2e,
                                      outf, nullptr, nullptr, xf, list, meta, meta, NTOK, D, FF, 0, 0, 1);

    layernorm_k<<<NTOK, 256, 0, stream>>>(outf, nullptr, 0, g2, b2, outf, meta);
}

// Round 6
// 782.535 us; speedup vs baseline: 3.1580x; 1.8523x over previous
//
#include <hip/hip_runtime.h>

// Problem constants (reference file)
#define D   1024
#define H   16
#define DH  64
#define FF  4096
#define E   4
#define BSZ 2
#define TT  2048
#define NTOK (BSZ*TT)   // 4096 tokens

typedef unsigned short u16;
typedef __attribute__((ext_vector_type(8))) short bf16x8;   // 8 bf16 = 4 VGPRs (MFMA A/B frag)
typedef __attribute__((ext_vector_type(4))) float f32x4;    // MFMA C/D frag

__device__ __forceinline__ float us2f(u16 u) {
    return __uint_as_float(((unsigned int)u) << 16);  // bf16 -> f32 exact
}
__device__ __forceinline__ u16 f2bf_rn(float f) {     // f32 -> bf16 round-to-nearest-even
    unsigned u = __float_as_uint(f);
    return (u16)((u + 0x7FFFu + ((u >> 16) & 1u)) >> 16);
}

// Panel layout: element offset of (row, k) in a [rows][K] operand stored as
// [row>>7][k>>5][(k>>3)&3][row&127][k&7]  (8KB per 128x32 K-step tile ==
// exactly the LDS staging image -> staging is a coalesced linear copy).
__device__ __forceinline__ size_t poff(int row, int k, int K) {
    return ((size_t)(row >> 7) * (K >> 5) + (k >> 5)) * 4096
         + (size_t)(((k >> 3) & 3) * 1024 + (row & 127) * 8 + (k & 7));
}

// async global->LDS, 16B per lane; LDS dest = wave-uniform base + lane*16
#define GLL16(gsrc, ldst) \
    __builtin_amdgcn_global_load_lds((const __attribute__((address_space(1))) void*)(gsrc), \
                                     (__attribute__((address_space(3))) void*)(ldst), 16, 0, 0)

// ---------------------------------------------------------------------------
// Dtype probe. Zero-inits expert counters.
// ---------------------------------------------------------------------------
__global__ __launch_bounds__(64) void probe_k(const unsigned* __restrict__ xw,
                                              int* __restrict__ meta) {
    const int lane = threadIdx.x;
    int wild = 0;
    for (int i = 0; i < 32; i++) {
        unsigned u = xw[lane * 32 + i];
        unsigned lo = u & 0xFFFFu;
        if ((lo & 0x7F80u) >= 0x5A00u) wild++;
    }
#pragma unroll
    for (int m = 32; m > 0; m >>= 1) wild += __shfl_xor(wild, m, 64);
    if (lane == 0) meta[4] = (wild < 64) ? 1 : 0;   // 1 = bf16 inputs, 0 = f32
    if (lane < 4) meta[lane] = 0;                   // expert counters
}

// ---------------------------------------------------------------------------
// Split x into bf16 hi/lo PANEL-layout tensors (rows x D).
// ---------------------------------------------------------------------------
__global__ __launch_bounds__(256) void xsplit_k(const void* __restrict__ in,
    u16* __restrict__ hi, u16* __restrict__ lo, const int* __restrict__ meta)
{
    const int i = blockIdx.x * 256 + threadIdx.x;
    const int flat = i * 4;
    const int row = flat >> 10, k = flat & 1023;    // D=1024
    float4 v;
    if (meta && meta[4]) {
        ushort4 u = ((const ushort4*)in)[i];
        v = make_float4(us2f(u.x), us2f(u.y), us2f(u.z), us2f(u.w));
    } else {
        v = ((const float4*)in)[i];
    }
    ushort4 h, l;
    h.x = f2bf_rn(v.x); l.x = f2bf_rn(v.x - us2f(h.x));
    h.y = f2bf_rn(v.y); l.y = f2bf_rn(v.y - us2f(h.y));
    h.z = f2bf_rn(v.z); l.z = f2bf_rn(v.z - us2f(h.z));
    h.w = f2bf_rn(v.w); l.w = f2bf_rn(v.w - us2f(h.w));
    size_t off = poff(row, k, D);                   // (k&7) in {0,4}: aligned
    *(ushort4*)&hi[off] = h;
    *(ushort4*)&lo[off] = l;
}

// ---------------------------------------------------------------------------
// Weight transpose + split: W[e][K][N] -> panel-layout T{hi,lo}[e] ([N][K]).
// ---------------------------------------------------------------------------
__global__ __launch_bounds__(256) void wtrans_k(const void* __restrict__ Wsrc,
    u16* __restrict__ Thi, u16* __restrict__ Tlo,
    int K, int N, const int* __restrict__ meta)
{
    const int bfm = meta[4];
    const int e = blockIdx.z;
    const int k0 = blockIdx.x * 64, n0 = blockIdx.y * 64;
    __shared__ float t[64][65];
    const int tid = threadIdx.x;
    const size_t sbase = (size_t)e * K * N;
#pragma unroll
    for (int rr = 0; rr < 4; rr++) {
        int row = rr * 16 + (tid >> 4);      // k
        int c4  = (tid & 15) * 4;            // n
        size_t off = sbase + (size_t)(k0 + row) * N + n0 + c4;
        float4 v;
        if (bfm) {
            ushort4 u = *(const ushort4*)((const u16*)Wsrc + off);
            v = make_float4(us2f(u.x), us2f(u.y), us2f(u.z), us2f(u.w));
        } else {
            v = *(const float4*)((const float*)Wsrc + off);
        }
        t[row][c4 + 0] = v.x; t[row][c4 + 1] = v.y;
        t[row][c4 + 2] = v.z; t[row][c4 + 3] = v.w;
    }
    __syncthreads();
#pragma unroll
    for (int rr = 0; rr < 4; rr++) {
        int nrow = n0 + rr * 16 + (tid >> 4);
        int k4   = k0 + (tid & 15) * 4;
        ushort4 h, l;
        float f0 = t[(k4 & 63) + 0][nrow - n0], f1 = t[(k4 & 63) + 1][nrow - n0];
        float f2 = t[(k4 & 63) + 2][nrow - n0], f3 = t[(k4 & 63) + 3][nrow - n0];
        h.x = f2bf_rn(f0); l.x = f2bf_rn(f0 - us2f(h.x));
        h.y = f2bf_rn(f1); l.y = f2bf_rn(f1 - us2f(h.y));
        h.z = f2bf_rn(f2); l.z = f2bf_rn(f2 - us2f(h.z));
        h.w = f2bf_rn(f3); l.w = f2bf_rn(f3 - us2f(h.w));
        size_t doff = (size_t)e * N * K + poff(nrow, k4, K);  // (k4&7) in {0,4}
        *(ushort4*)&Thi[doff] = h;
        *(ushort4*)&Tlo[doff] = l;
    }
}

// ---------------------------------------------------------------------------
// Expert base scan: meta[8+e] = 128-aligned exclusive cumsum of cnt.
// ---------------------------------------------------------------------------
__global__ __launch_bounds__(64) void scan_k(int* __restrict__ meta) {
    if (threadIdx.x == 0) {
        int b = 0;
#pragma unroll
        for (int e = 0; e < E; e++) {
            meta[8 + e] = b;
            b += (meta[e] + 127) & ~127;
        }
    }
}

// ---------------------------------------------------------------------------
// Gather x1 rows into expert-compacted PANEL layout (hi only; FF is 1-term).
// One wave per (expert, slot). Reads f32 xf rows coalesced.
// ---------------------------------------------------------------------------
__global__ __launch_bounds__(256) void gather_k(const float* __restrict__ xf,
    const int* __restrict__ list, const int* __restrict__ meta,
    u16* __restrict__ xg)
{
    const int e = blockIdx.z;
    const int r = blockIdx.x * 4 + (threadIdx.x >> 6);
    if (r >= meta[e]) return;
    const int lane = threadIdx.x & 63;
    const int t = list[e * NTOK + r];
    const int row_g = meta[8 + e] + r;
    const float* xr = xf + (size_t)t * D + lane * 16;
    u16 h[16];
#pragma unroll
    for (int j = 0; j < 16; j += 4) {
        float4 v = *(const float4*)(xr + j);
        h[j + 0] = f2bf_rn(v.x); h[j + 1] = f2bf_rn(v.y);
        h[j + 2] = f2bf_rn(v.z); h[j + 3] = f2bf_rn(v.w);
    }
    const int k0 = lane * 16;
#pragma unroll
    for (int g = 0; g < 2; g++) {                     // two 8-elem granules
        size_t off = poff(row_g, k0 + g * 8, D);
        *(ushort4*)&xg[off]     = make_ushort4(h[g*8+0], h[g*8+1], h[g*8+2], h[g*8+3]);
        *(ushort4*)&xg[off + 4] = make_ushort4(h[g*8+4], h[g*8+5], h[g*8+6], h[g*8+7]);
    }
}

// ---------------------------------------------------------------------------
// MFMA GEMM. TERMS=3: split-bf16 3-term compensation (QKV/Wo);
// TERMS=1: plain bf16 (FF1/FF2 — gate routing already fixed on f32 x1).
// All operands in PANEL layout -> staging is 8KB coalesced linear copies
// (GLL16 1KB/instr), double-buffered, one barrier per K-step.
// abase (meta rowbase) offsets compacted MoE rows. cpanel: write C in panel
// layout at compacted rows (FF1 -> h). Else C indexed by rowlist tokens.
// ---------------------------------------------------------------------------
template<int TERMS>
__global__ __launch_bounds__(256) void mgemm_k(
    const u16* __restrict__ Ahi, const u16* __restrict__ Alo,
    const u16* __restrict__ Bhi, const u16* __restrict__ Blo,
    const void* __restrict__ bias,                              // dual dtype
    float* __restrict__ Cf,                                     // f32 out (or null)
    u16* __restrict__ Chi, u16* __restrict__ Clo,               // bf16 out (Clo opt)
    const float* __restrict__ resid,
    const int* __restrict__ rowlist, const int* __restrict__ rowcnt,
    const int* __restrict__ rowbase,
    const int* __restrict__ meta, int M, int N, int K, int relu, int bias_row,
    int swz, int cpanel)
{
    const int bfm = meta[4];
    const int e = blockIdx.z;
    const int cnt = rowcnt ? rowcnt[e] : M;
    const int abase = rowbase ? rowbase[e] : 0;

    int bx = blockIdx.x, by = blockIdx.y;
    {
        const int gx = gridDim.x, gy = gridDim.y;
        int f = bx + gx * by;
        if (swz == 1 && (gx & 7) == 0) {
            int bandw = gx >> 3;
            int xcd = f & 7, r = f >> 3;
            bx = xcd * bandw + (r % bandw);
            by = r / bandw;
        } else if (swz == 2 && (gy & 7) == 0) {
            int bandh = gy >> 3;
            int xcd = f & 7, r = f >> 3;
            by = xcd * bandh + (r % bandh);
            bx = r / bandh;
        }
    }
    const int m0 = by * 128;
    if (m0 >= cnt) return;
    const int n0 = bx * 128;
    const int* lp = rowlist ? (rowlist + e * NTOK) : nullptr;

    constexpr int NA = (TERMS == 3) ? 4 : 2;
    __shared__ __attribute__((aligned(16))) u16 Ls[2][NA][4][128][8];

    const int tid = threadIdx.x;
    const int wave = tid >> 6, lane = tid & 63;
    const int wm = wave >> 1, wn = wave & 1;

    // staging role: T3: wave w -> array w, chunks 0..7.
    //               T1: arr = wave>>1 (0=A,1=B), chunks (wave&1)*4..+3.
    const char* sbase;          // byte base of this wave's panel row-block
    int arr, c0, nc;
    {
        const size_t arow_blk = (size_t)((abase + m0) >> 7) * (K >> 5) * 4096;
        const size_t brow_blk = (size_t)e * N * K + (size_t)(n0 >> 7) * (K >> 5) * 4096;
        if (TERMS == 3) {
            arr = wave; c0 = 0; nc = 8;
            const u16* sten = (wave == 0) ? Ahi : (wave == 1) ? Alo
                            : (wave == 2) ? Bhi : Blo;
            sbase = (const char*)(sten + ((wave < 2) ? arow_blk : brow_blk));
        } else {
            arr = wave >> 1; c0 = (wave & 1) * 4; nc = 4;
            const u16* sten = arr ? Bhi : Ahi;
            sbase = (const char*)(sten + (arr ? brow_blk : arow_blk));
        }
    }

    f32x4 acc[4][4];
#pragma unroll
    for (int mi = 0; mi < 4; mi++)
#pragma unroll
        for (int ni = 0; ni < 4; ni++) acc[mi][ni] = (f32x4){0.f, 0.f, 0.f, 0.f};

    const int lrow = lane & 15, kcl = lane >> 4;

#define MG_STAGE(buf, kstep) do {                                            \
        char* db = (char*)&Ls[buf][arr][0][0][0];                            \
        const char* sp = sbase + (size_t)(kstep) * 8192;                     \
        for (int c = c0; c < c0 + nc; c++)                                   \
            GLL16(sp + c * 1024 + lane * 16, db + c * 1024);                 \
    } while (0)

    MG_STAGE(0, 0);
    int cur = 0;
    const int nks = K >> 5;
    for (int ks = 0; ks < nks; ks++) {
        __syncthreads();                    // buf[cur] ready; prev reads done
        if (ks + 1 < nks) MG_STAGE(cur ^ 1, ks + 1);
        bf16x8 ah[4], al[4];
#pragma unroll
        for (int mi = 0; mi < 4; mi++) {
            int r = wm * 64 + mi * 16 + lrow;
            ah[mi] = *(const bf16x8*)&Ls[cur][0][kcl][r][0];
            if (TERMS == 3) al[mi] = *(const bf16x8*)&Ls[cur][1][kcl][r][0];
        }
#pragma unroll
        for (int ni = 0; ni < 4; ni++) {
            int c = wn * 64 + ni * 16 + lrow;
            bf16x8 bh = *(const bf16x8*)&Ls[cur][TERMS == 3 ? 2 : 1][kcl][c][0];
#pragma unroll
            for (int mi = 0; mi < 4; mi++)
                acc[mi][ni] = __builtin_amdgcn_mfma_f32_16x16x32_bf16(ah[mi], bh, acc[mi][ni], 0, 0, 0);
            if (TERMS == 3) {
                bf16x8 bl = *(const bf16x8*)&Ls[cur][3][kcl][c][0];
#pragma unroll
                for (int mi = 0; mi < 4; mi++) {
                    acc[mi][ni] = __builtin_amdgcn_mfma_f32_16x16x32_bf16(al[mi], bh, acc[mi][ni], 0, 0, 0);
                    acc[mi][ni] = __builtin_amdgcn_mfma_f32_16x16x32_bf16(ah[mi], bl, acc[mi][ni], 0, 0, 0);
                }
            }
        }
        cur ^= 1;
    }
#undef MG_STAGE

    // Epilogue. C/D frag layout: col = lane&15, row = (lane>>4)*4 + reg.
    float bval[4];
    if (!bias_row) {
#pragma unroll
        for (int ni = 0; ni < 4; ni++) {
            int col = n0 + wn * 64 + ni * 16 + (lane & 15);
            bval[ni] = bfm ? us2f(((const u16*)bias)[(size_t)e * N + col])
                           : ((const float*)bias)[(size_t)e * N + col];
        }
    }
#pragma unroll
    for (int mi = 0; mi < 4; mi++) {
#pragma unroll
        for (int rg = 0; rg < 4; rg++) {
            int row = m0 + wm * 64 + mi * 16 + (lane >> 4) * 4 + rg;
            if (row >= cnt) continue;
            float brow = 0.f;
            if (bias_row) brow = bfm ? us2f(((const u16*)bias)[(size_t)e * M + row])
                                     : ((const float*)bias)[(size_t)e * M + row];
#pragma unroll
            for (int ni = 0; ni < 4; ni++) {
                int col = n0 + wn * 64 + ni * 16 + (lane & 15);
                float v = acc[mi][ni][rg] + (bias_row ? brow : bval[ni]);
                if (cpanel) {
                    if (relu) v = fmaxf(v, 0.f);
                    size_t off = poff(abase + row, col, N);
                    Chi[off] = f2bf_rn(v);
                } else {
                    int tok = lp ? lp[row] : row;
                    size_t off = (size_t)tok * N + col;
                    if (resid) v += resid[off];
                    if (relu) v = fmaxf(v, 0.f);
                    if (Cf) {
                        Cf[off] = v;
                    } else {
                        u16 hh = f2bf_rn(v);
                        Chi[off] = hh;
                        if (Clo) Clo[off] = f2bf_rn(v - us2f(hh));
                    }
                }
            }
        }
    }
}

// ---------------------------------------------------------------------------
// MFMA causal flash attention, SPLIT-bf16 (3-term) — unchanged numerics from
// the passing R4/R5 kernel. Epilogue now writes PANEL-layout ahi/alo (feeds
// the Wo GEMM's coalesced staging).
// ---------------------------------------------------------------------------
__global__ __launch_bounds__(256) void attn_mfma(
    const u16* __restrict__ qh, const u16* __restrict__ ql,
    const u16* __restrict__ kh, const u16* __restrict__ kl,
    const u16* __restrict__ vth, const u16* __restrict__ vtl,
    u16* __restrict__ ohi, u16* __restrict__ olo)
{
    int bx = blockIdx.x, by = blockIdx.y;
    {
        int f = bx + (int)gridDim.x * by;
        int xcd = f & 7, r = f >> 3;
        const int bandh = (int)gridDim.y >> 3;
        by = xcd * bandh + (r % bandh);
        bx = r / bandh;
    }
    const int qi = (int)gridDim.x - 1 - bx;
    const int bh = by;
    const int b = bh >> 4, h = bh & 15;

    __shared__ __attribute__((aligned(16))) u16 KhL[4096];
    __shared__ __attribute__((aligned(16))) u16 KlL[4096];
    __shared__ __attribute__((aligned(16))) u16 VhL[4096];
    __shared__ __attribute__((aligned(16))) u16 VlL[4096];
    __shared__ __attribute__((aligned(16))) u16 PhL[4096];
    __shared__ __attribute__((aligned(16))) u16 PlL[4096];

    const int tid = threadIdx.x;
    const int wq = tid >> 6;
    const int lane = tid & 63;
    const int l15 = lane & 15, hl = lane >> 4;

    const int srow = lane >> 3;
    const int sg   = (lane & 7) ^ srow;
    const size_t qk_row = (size_t)D * 2;
    const size_t vt_row = (size_t)NTOK * 2;
    const size_t qk_base = (size_t)b * TT * qk_row + (size_t)h * 128;
    const size_t vt_base = (size_t)h * 64 * vt_row + (size_t)(b * TT) * 2;

    {
        const char* sh = (const char*)qh + qk_base + (size_t)(qi * 64) * qk_row;
        const char* sl = (const char*)ql + qk_base + (size_t)(qi * 64) * qk_row;
#pragma unroll
        for (int c = 0; c < 2; c++) {
            int r = wq * 16 + c * 8 + srow;
            size_t ro = (size_t)r * qk_row + (size_t)(sg * 16);
            GLL16(sh + ro, PhL + wq * 1024 + c * 512);
            GLL16(sl + ro, PlL + wq * 1024 + c * 512);
        }
    }

    float m_reg = -1e30f, l_reg = 0.f;
    f32x4 o[4];
#pragma unroll
    for (int nf = 0; nf < 4; nf++) o[nf] = (f32x4){0.f, 0.f, 0.f, 0.f};

    __syncthreads();
    bf16x8 qfh[2], qfl[2];
    {
        const int qrow = wq * 16 + l15;
#pragma unroll
        for (int ks = 0; ks < 2; ks++) {
            int qo = qrow * 64 + (((ks * 4 + hl) ^ (qrow & 7)) * 8);
            qfh[ks] = *(const bf16x8*)(PhL + qo);
            qfl[ks] = *(const bf16x8*)(PlL + qo);
        }
    }

    for (int kt = 0; kt <= qi; kt++) {
        __syncthreads();
        {
            const char* ksh = (const char*)kh + qk_base + (size_t)(kt * 64) * qk_row;
            const char* ksl = (const char*)kl + qk_base + (size_t)(kt * 64) * qk_row;
            const char* vsh = (const char*)vth + vt_base + (size_t)(kt * 64) * 2;
            const char* vsl = (const char*)vtl + vt_base + (size_t)(kt * 64) * 2;
#pragma unroll
            for (int c = 0; c < 2; c++) {
                int r = wq * 16 + c * 8 + srow;
                size_t ro = (size_t)r * qk_row + (size_t)(sg * 16);
                size_t vo = (size_t)r * vt_row + (size_t)(sg * 16);
                GLL16(ksh + ro, KhL + wq * 1024 + c * 512);
                GLL16(ksl + ro, KlL + wq * 1024 + c * 512);
                GLL16(vsh + vo, VhL + wq * 1024 + c * 512);
                GLL16(vsl + vo, VlL + wq * 1024 + c * 512);
            }
        }
        __syncthreads();

        f32x4 s[4];
#pragma unroll
        for (int mf = 0; mf < 4; mf++) s[mf] = (f32x4){0.f, 0.f, 0.f, 0.f};
#pragma unroll
        for (int ks = 0; ks < 2; ks++) {
#pragma unroll
            for (int mf = 0; mf < 4; mf++) {
                int row = mf * 16 + l15;
                int go = row * 64 + (((ks * 4 + hl) ^ (row & 7)) * 8);
                bf16x8 kfh = *(const bf16x8*)(KhL + go);
                bf16x8 kfl = *(const bf16x8*)(KlL + go);
                s[mf] = __builtin_amdgcn_mfma_f32_16x16x32_bf16(kfh, qfh[ks], s[mf], 0, 0, 0);
                s[mf] = __builtin_amdgcn_mfma_f32_16x16x32_bf16(kfl, qfh[ks], s[mf], 0, 0, 0);
                s[mf] = __builtin_amdgcn_mfma_f32_16x16x32_bf16(kfh, qfl[ks], s[mf], 0, 0, 0);
            }
        }
#pragma unroll
        for (int mf = 0; mf < 4; mf++) {
            s[mf][0] *= 0.125f; s[mf][1] *= 0.125f;
            s[mf][2] *= 0.125f; s[mf][3] *= 0.125f;
        }
        if (kt == qi) {
            const int ql_ = wq * 16 + l15;
#pragma unroll
            for (int mf = 0; mf < 4; mf++)
#pragma unroll
                for (int r = 0; r < 4; r++)
                    if (mf * 16 + hl * 4 + r > ql_) s[mf][r] = -1e30f;
        }
        float tm = fmaxf(fmaxf(s[0][0], s[0][1]), fmaxf(s[0][2], s[0][3]));
#pragma unroll
        for (int mf = 1; mf < 4; mf++)
            tm = fmaxf(tm, fmaxf(fmaxf(s[mf][0], s[mf][1]), fmaxf(s[mf][2], s[mf][3])));
        tm = fmaxf(tm, __shfl_xor(tm, 16, 64));
        tm = fmaxf(tm, __shfl_xor(tm, 32, 64));
        const float mn = fmaxf(m_reg, tm);
        const float a = (m_reg < -9e29f) ? 0.f : __expf(m_reg - mn);

        float ps = 0.f;
#pragma unroll
        for (int mf = 0; mf < 4; mf++) {
            float p0 = __expf(fmaxf(s[mf][0] - mn, -80.f));
            float p1 = __expf(fmaxf(s[mf][1] - mn, -80.f));
            float p2 = __expf(fmaxf(s[mf][2] - mn, -80.f));
            float p3 = __expf(fmaxf(s[mf][3] - mn, -80.f));
            ps += (p0 + p1) + (p2 + p3);
            u16 h0 = f2bf_rn(p0), h1 = f2bf_rn(p1), h2 = f2bf_rn(p2), h3 = f2bf_rn(p3);
            uint2 dh, dl;
            dh.x = ((unsigned)h1 << 16) | h0;
            dh.y = ((unsigned)h3 << 16) | h2;
            dl.x = ((unsigned)f2bf_rn(p1 - us2f(h1)) << 16) | f2bf_rn(p0 - us2f(h0));
            dl.y = ((unsigned)f2bf_rn(p3 - us2f(h3)) << 16) | f2bf_rn(p2 - us2f(h2));
            int kbyte = (mf * 16 + hl * 4) * 2;
            int addr = wq * 2048 + l15 * 128 + (kbyte ^ ((l15 & 7) << 4));
            *(uint2*)((char*)PhL + addr) = dh;
            *(uint2*)((char*)PlL + addr) = dl;
        }
        ps += __shfl_xor(ps, 16, 64);
        ps += __shfl_xor(ps, 32, 64);
        l_reg = l_reg * a + ps;
        m_reg = mn;

        {
            float a0 = __shfl(a, hl * 4 + 0, 64);
            float a1 = __shfl(a, hl * 4 + 1, 64);
            float a2 = __shfl(a, hl * 4 + 2, 64);
            float a3 = __shfl(a, hl * 4 + 3, 64);
#pragma unroll
            for (int nf = 0; nf < 4; nf++) {
                o[nf][0] *= a0; o[nf][1] *= a1; o[nf][2] *= a2; o[nf][3] *= a3;
            }
        }
        asm volatile("" ::: "memory");
#pragma unroll
        for (int ks = 0; ks < 2; ks++) {
            int po = wq * 1024 + l15 * 64 + (((ks * 4 + hl) ^ (l15 & 7)) * 8);
            bf16x8 pfh = *(const bf16x8*)(PhL + po);
            bf16x8 pfl = *(const bf16x8*)(PlL + po);
#pragma unroll
            for (int nf = 0; nf < 4; nf++) {
                int vrow = nf * 16 + l15;
                int vo = vrow * 64 + (((ks * 4 + hl) ^ (vrow & 7)) * 8);
                bf16x8 vfh = *(const bf16x8*)(VhL + vo);
                bf16x8 vfl = *(const bf16x8*)(VlL + vo);
                o[nf] = __builtin_amdgcn_mfma_f32_16x16x32_bf16(pfh, vfh, o[nf], 0, 0, 0);
                o[nf] = __builtin_amdgcn_mfma_f32_16x16x32_bf16(pfl, vfh, o[nf], 0, 0, 0);
                o[nf] = __builtin_amdgcn_mfma_f32_16x16x32_bf16(pfh, vfl, o[nf], 0, 0, 0);
            }
        }
    }

    // epilogue: PANEL-layout output (rows = tokens, cols = D)
    const float linv = 1.f / l_reg;
    float lia[4];
    lia[0] = __shfl(linv, hl * 4 + 0, 64);
    lia[1] = __shfl(linv, hl * 4 + 1, 64);
    lia[2] = __shfl(linv, hl * 4 + 2, 64);
    lia[3] = __shfl(linv, hl * 4 + 3, 64);
#pragma unroll
    for (int r = 0; r < 4; r++) {
        int arow = b * TT + qi * 64 + wq * 16 + hl * 4 + r;
#pragma unroll
        for (int nf = 0; nf < 4; nf++) {
            int acol = h * 64 + nf * 16 + l15;
            float vv = o[nf][r] * lia[r];
            u16 hh = f2bf_rn(vv);
            size_t off = poff(arow, acol, D);
            ohi[off] = hh;
            olo[off] = f2bf_rn(vv - us2f(hh));
        }
    }
}

// ---------------------------------------------------------------------------
// LayerNorm over D=1024 (in-place safe). Residual optionally dual-dtype raw input.
// ---------------------------------------------------------------------------
__global__ __launch_bounds__(256) void layernorm_k(const float* __restrict__ a,
    const void* __restrict__ resid, int rdual, const void* __restrict__ g_,
    const void* __restrict__ b_, float* __restrict__ out,
    const int* __restrict__ meta)
{
    const int bfm = meta[4];
    const int row = blockIdx.x;
    const int tid = threadIdx.x;
    float vals[4];
    float s = 0.f, s2 = 0.f;
#pragma unroll
    for (int i = 0; i < 4; i++) {
        int idx = tid + (i << 8);
        size_t off = (size_t)row * D + idx;
        float v = a[off];
        if (resid) {
            float rv = (rdual && bfm) ? us2f(((const u16*)resid)[off])
                                      : ((const float*)resid)[off];
            v += rv;
        }
        vals[i] = v; s += v; s2 += v * v;
    }
#pragma unroll
    for (int msk = 32; msk > 0; msk >>= 1) {
        s  += __shfl_xor(s,  msk, 64);
        s2 += __shfl_xor(s2, msk, 64);
    }
    __shared__ float red[2][4];
    if ((tid & 63) == 0) { red[0][tid >> 6] = s; red[1][tid >> 6] = s2; }
    __syncthreads();
    s  = red[0][0] + red[0][1] + red[0][2] + red[0][3];
    s2 = red[1][0] + red[1][1] + red[1][2] + red[1][3];
    const float mu = s * (1.f / D);
    const float var = s2 * (1.f / D) - mu * mu;
    const float rs = rsqrtf(var + 1e-5f);
#pragma unroll
    for (int i = 0; i < 4; i++) {
        int idx = tid + (i << 8);
        float gg = bfm ? us2f(((const u16*)g_)[idx]) : ((const float*)g_)[idx];
        float bb = bfm ? us2f(((const u16*)b_)[idx]) : ((const float*)b_)[idx];
        out[(size_t)row * D + idx] = (vals[i] - mu) * rs * gg + bb;
    }
}

// ---------------------------------------------------------------------------
// Top-1 gate in fp32 + bucket scatter. One wave per token.
// ---------------------------------------------------------------------------
__global__ __launch_bounds__(256) void gate_k(const float* __restrict__ x1,
    const void* __restrict__ Wg, const void* __restrict__ bg,
    int* __restrict__ cnt, int* __restrict__ list, const int* __restrict__ meta)
{
    const int bfm = meta[4];
    const int tok = (blockIdx.x * 256 + threadIdx.x) >> 6;
    const int lane = threadIdx.x & 63;
    const float* xr = x1 + (size_t)tok * D;
    float s0 = 0.f, s1 = 0.f, s2 = 0.f, s3 = 0.f;
    for (int d = lane; d < D; d += 64) {
        float xv = xr[d];
        float w0, w1, w2, w3;
        if (bfm) {
            ushort4 wu = ((const ushort4*)Wg)[d];
            w0 = us2f(wu.x); w1 = us2f(wu.y); w2 = us2f(wu.z); w3 = us2f(wu.w);
        } else {
            float4 wf = ((const float4*)Wg)[d];
            w0 = wf.x; w1 = wf.y; w2 = wf.z; w3 = wf.w;
        }
        s0 += xv * w0; s1 += xv * w1; s2 += xv * w2; s3 += xv * w3;
    }
#pragma unroll
    for (int msk = 32; msk > 0; msk >>= 1) {
        s0 += __shfl_xor(s0, msk, 64); s1 += __shfl_xor(s1, msk, 64);
        s2 += __shfl_xor(s2, msk, 64); s3 += __shfl_xor(s3, msk, 64);
    }
    if (lane == 0) {
        float g0, g1, g2, g3;
        if (bfm) {
            g0 = us2f(((const u16*)bg)[0]); g1 = us2f(((const u16*)bg)[1]);
            g2 = us2f(((const u16*)bg)[2]); g3 = us2f(((const u16*)bg)[3]);
        } else {
            g0 = ((const float*)bg)[0]; g1 = ((const float*)bg)[1];
            g2 = ((const float*)bg)[2]; g3 = ((const float*)bg)[3];
        }
        float b0 = s0 + g0, b1 = s1 + g1, b2 = s2 + g2, b3 = s3 + g3;
        int bi = 0; float best = b0;
        if (b1 > best) { best = b1; bi = 1; }
        if (b2 > best) { best = b2; bi = 2; }
        if (b3 > best) { best = b3; bi = 3; }
        int slot = atomicAdd(&cnt[bi], 1);
        list[bi * NTOK + slot] = tok;
    }
}

// ---------------------------------------------------------------------------
extern "C" void kernel_launch(void* const* d_in, const int* in_sizes, int n_in,
                              void* d_out, int out_size, void* d_ws, size_t ws_size,
                              hipStream_t stream)
{
    const void* x  = d_in[0];
    const void* Wq = d_in[2];  const void* bq = d_in[3];
    const void* Wk = d_in[4];  const void* bk = d_in[5];
    const void* Wv = d_in[6];  const void* bv = d_in[7];
    const void* Wo = d_in[8];  const void* bo = d_in[9];
    const void* g1 = d_in[10]; const void* b1 = d_in[11];
    const void* Wg = d_in[12]; const void* bg = d_in[13];
    const void* W1e = d_in[14]; const void* b1e = d_in[15];
    const void* W2e = d_in[16]; const void* b2e = d_in[17];
    const void* g2 = d_in[18]; const void* b2 = d_in[19];

    const size_t NE  = (size_t)NTOK * D;   // 4M elems
    const size_t NE4 = NE * 4;
    const size_t NEU = NE * 2;             // bytes of one u16 NTOK x D tensor
    char* W = (char*)d_ws;
    // layout (bytes):
    float* xf   = (float*)W;                                    // 16.8M f32
    float* buf0 = (float*)(W + NE4);                            // 16.8M f32
    int*   meta = (int*)(W + 2 * NE4);                          // 128K
    int*   list = meta + 16;
    char*  p = W + 2 * NE4 + 131072;
    u16* xhi = (u16*)p;            u16* xlo = xhi + NE;  p += 2 * NEU;  // x panels
    u16* qhi = (u16*)p;            u16* qlo = qhi + NE;  p += 2 * NEU;  // [tok][D]
    u16* khi = (u16*)p;            u16* klo = khi + NE;  p += 2 * NEU;
    u16* vthi = (u16*)p;           u16* vtlo = vthi + NE; p += 2 * NEU; // [dcol][tok]
    u16* ahi = (u16*)p;            u16* alo = ahi + NE;  p += 2 * NEU;  // attn panels
    u16* whi = (u16*)p;            u16* wlo = whi + (size_t)NTOK * FF;
    p += 2 * (size_t)NTOK * FF * 2;
    // overlays (lifetimes disjoint):
    u16* xg  = (u16*)qhi;                       // (NTOK+512)xD panel, 9.4M <= q region
    u16* hhi = (u16*)khi;                       // (NTOK+512)xFF panel, 37.7M over k+vt+a
    float* outf = (float*)d_out;

    probe_k<<<1, 64, 0, stream>>>((const unsigned*)x, meta);
    xsplit_k<<<(int)(NE / 4 / 256), 256, 0, stream>>>(x, xhi, xlo, meta);

    const size_t DD = (size_t)D * D;
    wtrans_k<<<dim3(D / 64, D / 64, 1), 256, 0, stream>>>(Wq, whi + 0 * DD, wlo + 0 * DD, D, D, meta);
    wtrans_k<<<dim3(D / 64, D / 64, 1), 256, 0, stream>>>(Wk, whi + 1 * DD, wlo + 1 * DD, D, D, meta);
    wtrans_k<<<dim3(D / 64, D / 64, 1), 256, 0, stream>>>(Wv, whi + 2 * DD, wlo + 2 * DD, D, D, meta);
    wtrans_k<<<dim3(D / 64, D / 64, 1), 256, 0, stream>>>(Wo, whi + 3 * DD, wlo + 3 * DD, D, D, meta);

    dim3 gqkv(D / 128, NTOK / 128, 1);
    mgemm_k<3><<<gqkv, 256, 0, stream>>>(xhi, xlo, whi + 0 * DD, wlo + 0 * DD, bq, nullptr,
        qhi, qlo, nullptr, nullptr, nullptr, nullptr, meta, NTOK, D, D, 0, 0, 2, 0);
    mgemm_k<3><<<gqkv, 256, 0, stream>>>(xhi, xlo, whi + 1 * DD, wlo + 1 * DD, bk, nullptr,
        khi, klo, nullptr, nullptr, nullptr, nullptr, meta, NTOK, D, D, 0, 0, 2, 0);
    mgemm_k<3><<<dim3(NTOK / 128, D / 128, 1), 256, 0, stream>>>(whi + 2 * DD, wlo + 2 * DD, xhi, xlo, bv, nullptr,
        vthi, vtlo, nullptr, nullptr, nullptr, nullptr, meta, D, NTOK, D, 0, 1, 1, 0);

    attn_mfma<<<dim3(TT / 64, BSZ * H), 256, 0, stream>>>(qhi, qlo, khi, klo, vthi, vtlo, ahi, alo);

    mgemm_k<3><<<gqkv, 256, 0, stream>>>(ahi, alo, whi + 3 * DD, wlo + 3 * DD, bo, buf0,
        nullptr, nullptr, nullptr, nullptr, nullptr, nullptr, meta, NTOK, D, D, 0, 0, 2, 0);
    layernorm_k<<<NTOK, 256, 0, stream>>>(buf0, x, 1, g1, b1, xf, meta);

    gate_k<<<NTOK / 4, 256, 0, stream>>>(xf, Wg, bg, meta, list, meta);
    scan_k<<<1, 64, 0, stream>>>(meta);
    gather_k<<<dim3(NTOK / 4, 1, E), 256, 0, stream>>>(xf, list, meta, xg);

    wtrans_k<<<dim3(D / 64, FF / 64, E), 256, 0, stream>>>(W1e, whi, wlo, D, FF, meta);
    mgemm_k<1><<<dim3(FF / 128, NTOK / 128, E), 256, 0, stream>>>(xg, nullptr, whi, nullptr, b1e,
        nullptr, hhi, nullptr, nullptr, nullptr, meta, meta + 8, meta, NTOK, FF, D, 1, 0, 1, 1);

    wtrans_k<<<dim3(FF / 64, D / 64, E), 256, 0, stream>>>(W2e, whi, wlo, FF, D, meta);
    mgemm_k<1><<<dim3(D / 128, NTOK / 128, E), 256, 0, stream>>>(hhi, nullptr, whi, nullptr, b2e,
        outf, nullptr, nullptr, xf, list, meta, meta + 8, meta, NTOK, D, FF, 0, 0, 1, 0);

    layernorm_k<<<NTOK, 256, 0, stream>>>(outf, nullptr, 0, g2, b2, outf, meta);
}